// Round 19
// baseline (2297.181 us; speedup 1.0000x reference)
//
#include <hip/hip_runtime.h>
#include <hip/hip_bf16.h>

#define NB    32768
#define NIN   1024
#define NHID  2048
#define NLAT  64
#define NEMB  4096
#define BETA  0.25f
#define TAU   0.004f

#define FLTMAX 3.402823466e+38f

// ---- output layout (FLOAT32 elements) ----
#define XR_OFF   0
#define ZE_OFF   33554432
#define ZQ_OFF   35651584
#define IDX_OFF  37748736
#define LOSS_OFF 37781504

// ---- ws layout (bytes) — IDENTICAL to the R17 proven map (max 17,190,912) ----
#define PART_WS_F   0          // 512 f32 loss partials
#define ESQ_WS_B    4096       // 4096 f32
#define W1T_WS_B    20480      // dec w1t bf16 [2048][64]
#define W2T_WS_B    282624     // dec w2t bf16 [1024][2048] -> ends 4476928
#define W1HT_WS_B   4476928    // enc w1 split hi  bf16 [2048 h][1024 k]
#define W1MT_WS_B   8671232    // enc w1 split mid
#define W1LT_WS_B   12865536   // enc w1 split lo  -> ends 17059840
#define FLAGS_WS_B  17059840   // 32768 f32 gaps -> ends 17190912

typedef short v8s __attribute__((ext_vector_type(8)));
typedef float v4f __attribute__((ext_vector_type(4)));

static __device__ __forceinline__ unsigned short f2bf(float f) {
    union { __hip_bfloat16 h; unsigned short u; } v;
    v.h = __float2bfloat16(f);
    return v.u;
}

// exact truncation split: v == bh + bm + bl (as bf16-representable f32s)
static __device__ __forceinline__ void split3(float v, unsigned short& h,
                                              unsigned short& m, unsigned short& l) {
    unsigned int u = __float_as_uint(v);
    h = (unsigned short)(u >> 16);
    float r1 = v - __uint_as_float(u & 0xFFFF0000u);
    unsigned int u1 = __float_as_uint(r1);
    m = (unsigned short)(u1 >> 16);
    float r2 = r1 - __uint_as_float(u1 & 0xFFFF0000u);
    l = (unsigned short)(__float_as_uint(r2) >> 16);
}

// ---------------- codebook norms ----------------
__global__ void esq_kernel(const float* __restrict__ cb, float* __restrict__ esq) {
    int c = blockIdx.x * 256 + threadIdx.x;
    float s = 0.f;
#pragma unroll
    for (int d4 = 0; d4 < NLAT; d4 += 4) {
        float4 v = *reinterpret_cast<const float4*>(&cb[(size_t)c * NLAT + d4]);
        s += v.x * v.x; s += v.y * v.y; s += v.z * v.z; s += v.w * v.w;
    }
    esq[c] = s;
}

// ---------------- prep: decoder weights ----------------
__global__ void prep_w1t(const float* __restrict__ dw1, unsigned short* __restrict__ w1t) {
    int idx = blockIdx.x * 256 + threadIdx.x;
    int l = idx >> 11, h = idx & 2047;
    w1t[h * 64 + l] = f2bf(dw1[l * 2048 + h]);
}
__global__ void prep_w2t(const float* __restrict__ dw2, unsigned short* __restrict__ w2t) {
    int idx = blockIdx.x * 256 + threadIdx.x;
    int k = idx >> 10, c = idx & 1023;
    w2t[(size_t)c * 2048 + k] = f2bf(dw2[(size_t)k * 1024 + c]);
}

// ---------------- prep: encoder w1 transpose + 3-way bf16 split ----------------
__global__ void prep_w1split(const float* __restrict__ w1,
                             unsigned short* __restrict__ w1hT,
                             unsigned short* __restrict__ w1mT,
                             unsigned short* __restrict__ w1lT) {
    __shared__ __align__(16) float tile[64][68];
    int kb = blockIdx.x & 15, hb = blockIdx.x >> 4;
    int k0 = kb * 64, h0 = hb * 64;
    int r = threadIdx.x >> 4, c4 = (threadIdx.x & 15) * 4;
#pragma unroll
    for (int i = 0; i < 4; i++) {
        int rr = r + 16 * i;
        float4 v = *reinterpret_cast<const float4*>(&w1[(size_t)(k0 + rr) * NHID + h0 + c4]);
        tile[rr][c4 + 0] = v.x; tile[rr][c4 + 1] = v.y;
        tile[rr][c4 + 2] = v.z; tile[rr][c4 + 3] = v.w;
    }
    __syncthreads();
#pragma unroll
    for (int i = 0; i < 4; i++) {
        int hh = r + 16 * i;
        unsigned short sh[4], sm[4], sl[4];
#pragma unroll
        for (int j = 0; j < 4; j++) {
            split3(tile[c4 + j][hh], sh[j], sm[j], sl[j]);
        }
        size_t addr = (size_t)(h0 + hh) * 1024 + k0 + c4;
        *reinterpret_cast<ushort4*>(&w1hT[addr]) = make_ushort4(sh[0], sh[1], sh[2], sh[3]);
        *reinterpret_cast<ushort4*>(&w1mT[addr]) = make_ushort4(sm[0], sm[1], sm[2], sm[3]);
        *reinterpret_cast<ushort4*>(&w1lT[addr]) = make_ushort4(sl[0], sl[1], sl[2], sl[3]);
    }
}

// ---------------- fused encoder (MFMA 3-split) + GEMM2 (fp32) + VQ top-2 ----------------
// R17 verbatim (proven end-to-end incl. graph replay).
__global__ __launch_bounds__(512)
void encvq_kernel(const float* __restrict__ x,
                  const unsigned short* __restrict__ w1hT,
                  const unsigned short* __restrict__ w1mT,
                  const unsigned short* __restrict__ w1lT,
                  const float* __restrict__ b1, const float* __restrict__ w2,
                  const float* __restrict__ b2, const float* __restrict__ cb,
                  const float* __restrict__ esq,
                  float* __restrict__ out, float* __restrict__ partials,
                  float* __restrict__ flags) {
    float* ze_out  = out + ZE_OFF;
    float* zq_out  = out + ZQ_OFF;
    float* idx_out = out + IDX_OFF;

    static __shared__ __align__(16) unsigned char smem[76800];
    unsigned short* xh  = (unsigned short*)(smem);
    unsigned short* xm  = (unsigned short*)(smem + 5120);
    unsigned short* xl  = (unsigned short*)(smem + 10240);
    unsigned short* bsh = (unsigned short*)(smem + 15360);
    unsigned short* bsm = (unsigned short*)(smem + 35840);
    unsigned short* bsl = (unsigned short*)(smem + 56320);
    float* hs  = (float*)(smem);
    float* w2s = (float*)(smem + 10240);
    float* zs  = (float*)(smem);
    float* cbs = (float*)(smem + 16384);
    __shared__ int   ridx2[64];
    __shared__ float zsq[64];
    __shared__ float lred[64];

    const int t = threadIdx.x;
    const int rg = t >> 5, cg = t & 31;
    const int wv = t >> 6, lane = t & 63;
    const int wr = wv >> 2, wc = wv & 3;
    const int lo = lane & 15, hi = lane >> 4;
    const int brow = blockIdx.x * 64;

    float2 zacc[4];
#pragma unroll
    for (int i = 0; i < 4; i++) zacc[i] = make_float2(0.f, 0.f);

    for (int jc = 0; jc < NHID; jc += 256) {
        // -------- GEMM1 (MFMA) --------
        v4f acc[2][4];
#pragma unroll
        for (int rt = 0; rt < 2; rt++)
#pragma unroll
            for (int ct = 0; ct < 4; ct++) acc[rt][ct] = (v4f){0.f, 0.f, 0.f, 0.f};

        for (int kc = 0; kc < NIN; kc += 32) {
            __syncthreads();
            {
                int row = t >> 3, seg = t & 7;
                float4 v = *reinterpret_cast<const float4*>(
                    &x[(size_t)(brow + row) * NIN + kc + seg * 4]);
                unsigned short sh[4], sm[4], sl[4];
                split3(v.x, sh[0], sm[0], sl[0]);
                split3(v.y, sh[1], sm[1], sl[1]);
                split3(v.z, sh[2], sm[2], sl[2]);
                split3(v.w, sh[3], sm[3], sl[3]);
                int a = row * 40 + seg * 4;
                *reinterpret_cast<ushort4*>(&xh[a]) = make_ushort4(sh[0], sh[1], sh[2], sh[3]);
                *reinterpret_cast<ushort4*>(&xm[a]) = make_ushort4(sm[0], sm[1], sm[2], sm[3]);
                *reinterpret_cast<ushort4*>(&xl[a]) = make_ushort4(sl[0], sl[1], sl[2], sl[3]);
            }
#pragma unroll
            for (int jj = 0; jj < 2; jj++) {
                int col = (t >> 2) + 128 * jj, segb = t & 3;
                size_t src = (size_t)(jc + col) * 1024 + kc + segb * 8;
                int dst = col * 40 + segb * 8;
                *reinterpret_cast<uint4*>(&bsh[dst]) = *reinterpret_cast<const uint4*>(&w1hT[src]);
                *reinterpret_cast<uint4*>(&bsm[dst]) = *reinterpret_cast<const uint4*>(&w1mT[src]);
                *reinterpret_cast<uint4*>(&bsl[dst]) = *reinterpret_cast<const uint4*>(&w1lT[src]);
            }
            __syncthreads();

            v8s Ah[2], Am[2], Al[2];
#pragma unroll
            for (int rt = 0; rt < 2; rt++) {
                int ra = (32 * wr + 16 * rt + lo) * 40 + hi * 8;
                Ah[rt] = *reinterpret_cast<const v8s*>(&xh[ra]);
                Am[rt] = *reinterpret_cast<const v8s*>(&xm[ra]);
                Al[rt] = *reinterpret_cast<const v8s*>(&xl[ra]);
            }
#pragma unroll
            for (int ct = 0; ct < 4; ct++) {
                int ba = (64 * wc + 16 * ct + lo) * 40 + hi * 8;
                v8s Bh = *reinterpret_cast<const v8s*>(&bsh[ba]);
                v8s Bm = *reinterpret_cast<const v8s*>(&bsm[ba]);
                v8s Bl = *reinterpret_cast<const v8s*>(&bsl[ba]);
#pragma unroll
                for (int rt = 0; rt < 2; rt++) {
                    acc[rt][ct] = __builtin_amdgcn_mfma_f32_16x16x32_bf16(Ah[rt], Bh, acc[rt][ct], 0, 0, 0);
                    acc[rt][ct] = __builtin_amdgcn_mfma_f32_16x16x32_bf16(Ah[rt], Bm, acc[rt][ct], 0, 0, 0);
                    acc[rt][ct] = __builtin_amdgcn_mfma_f32_16x16x32_bf16(Am[rt], Bh, acc[rt][ct], 0, 0, 0);
                    acc[rt][ct] = __builtin_amdgcn_mfma_f32_16x16x32_bf16(Ah[rt], Bl, acc[rt][ct], 0, 0, 0);
                    acc[rt][ct] = __builtin_amdgcn_mfma_f32_16x16x32_bf16(Al[rt], Bh, acc[rt][ct], 0, 0, 0);
                    acc[rt][ct] = __builtin_amdgcn_mfma_f32_16x16x32_bf16(Am[rt], Bm, acc[rt][ct], 0, 0, 0);
                }
            }
        }

        // -------- GEMM2 (fp32) --------
        for (int cs = 0; cs < 8; cs++) {
            __syncthreads();
            if (wc == (cs >> 1)) {
                int ctp = (cs & 1) * 2;
#pragma unroll
                for (int c2 = 0; c2 < 2; c2++) {
                    int ct2 = ctp + c2;
                    float bias = b1[jc + 64 * wc + 16 * ct2 + lo];
#pragma unroll
                    for (int rt = 0; rt < 2; rt++) {
#pragma unroll
                        for (int r = 0; r < 4; r++) {
                            int rl = 32 * wr + 16 * rt + 4 * hi + r;
                            hs[rl * 36 + 16 * c2 + lo] = fmaxf(acc[rt][ct2][r] + bias, 0.f);
                        }
                    }
                }
            }
            {
                int r = t >> 4, c4 = (t & 15) * 4;
                *reinterpret_cast<float4*>(&w2s[r * 68 + c4]) =
                    *reinterpret_cast<const float4*>(&w2[(size_t)(jc + 32 * cs + r) * NLAT + c4]);
            }
            __syncthreads();
#pragma unroll 4
            for (int k = 0; k < 32; k++) {
                float2 wvv = *reinterpret_cast<float2*>(&w2s[k * 68 + cg * 2]);
#pragma unroll
                for (int i = 0; i < 4; i++) {
                    float hv = hs[(rg + 16 * i) * 36 + k];
                    zacc[i].x += hv * wvv.x;
                    zacc[i].y += hv * wvv.y;
                }
            }
        }
    }

    __syncthreads();
    {
        float2 b2v = *reinterpret_cast<const float2*>(&b2[cg * 2]);
#pragma unroll
        for (int i = 0; i < 4; i++) {
            int row = brow + rg + 16 * i;
            float2 z = make_float2(zacc[i].x + b2v.x, zacc[i].y + b2v.y);
            *reinterpret_cast<float2*>(&zs[(rg + 16 * i) * 64 + cg * 2]) = z;
            *reinterpret_cast<float2*>(&ze_out[(size_t)row * NLAT + cg * 2]) = z;
        }
    }
    __syncthreads();

    // ---------------- VQ with top-2 tracking ----------------
    if (t < 64) {
        float s = 0.f;
#pragma unroll 16
        for (int d = 0; d < 64; d++) { float v = zs[t * 64 + d]; s += v * v; }
        zsq[t] = s;
    }
    __syncthreads();
    float zr[4];
#pragma unroll
    for (int i = 0; i < 4; i++) zr[i] = zsq[rg + 16 * i];

    float best[4], b2nd[4]; int bidx[4];
#pragma unroll
    for (int i = 0; i < 4; i++) { best[i] = FLTMAX; b2nd[i] = FLTMAX; bidx[i] = 0; }

    for (int cc = 0; cc < NEMB; cc += 128) {
        __syncthreads();
#pragma unroll
        for (int jj = 0; jj < 4; jj++) {
            int id = t + 512 * jj;
            int r = id >> 4, c4 = (id & 15) * 4;
            *reinterpret_cast<float4*>(&cbs[r * 68 + c4]) =
                *reinterpret_cast<const float4*>(&cb[(size_t)(cc + r) * NLAT + c4]);
        }
        __syncthreads();
        float dot[4][4];
#pragma unroll
        for (int i = 0; i < 4; i++)
#pragma unroll
            for (int j = 0; j < 4; j++) dot[i][j] = 0.f;
#pragma unroll 2
        for (int d4 = 0; d4 < 64; d4 += 4) {
            float4 zv[4];
#pragma unroll
            for (int i = 0; i < 4; i++)
                zv[i] = *reinterpret_cast<float4*>(&zs[(rg + 16 * i) * 64 + d4]);
#pragma unroll
            for (int j = 0; j < 4; j++) {
                float4 cv = *reinterpret_cast<float4*>(&cbs[(cg + 32 * j) * 68 + d4]);
#pragma unroll
                for (int i = 0; i < 4; i++) {
                    dot[i][j] += zv[i].x*cv.x + zv[i].y*cv.y + zv[i].z*cv.z + zv[i].w*cv.w;
                }
            }
        }
#pragma unroll
        for (int j = 0; j < 4; j++) {
            int cl = cg + 32 * j;
            float eq = esq[cc + cl];
#pragma unroll
            for (int i = 0; i < 4; i++) {
                float d2 = (zr[i] - 2.f * dot[i][j]) + eq;
                int c = cc + cl;
                if (d2 < best[i] || (d2 == best[i] && c < bidx[i])) {
                    b2nd[i] = fminf(best[i], b2nd[i]);
                    best[i] = d2; bidx[i] = c;
                } else {
                    b2nd[i] = fminf(b2nd[i], d2);
                }
            }
        }
    }
#pragma unroll
    for (int off = 16; off >= 1; off >>= 1) {
#pragma unroll
        for (int i = 0; i < 4; i++) {
            float ob  = __shfl_xor(best[i], off, 64);
            int   oi  = __shfl_xor(bidx[i], off, 64);
            float ob2 = __shfl_xor(b2nd[i], off, 64);
            if (ob < best[i] || (ob == best[i] && oi < bidx[i])) {
                b2nd[i] = fminf(best[i], ob2);
                best[i] = ob; bidx[i] = oi;
            } else {
                b2nd[i] = fminf(b2nd[i], ob);
            }
        }
    }
    if (cg == 0) {
#pragma unroll
        for (int i = 0; i < 4; i++) {
            ridx2[rg + 16 * i] = bidx[i];
            flags[brow + rg + 16 * i] = b2nd[i] - best[i];
        }
    }
    __syncthreads();
    if (t < 64) {
        int c = ridx2[t] & (NEMB - 1);
        int row = brow + t;
        idx_out[row] = (float)c;
        float s = 0.f;
#pragma unroll
        for (int d4 = 0; d4 < 64; d4 += 4) {
            float4 q = *reinterpret_cast<const float4*>(&cb[(size_t)c * NLAT + d4]);
            float z0 = zs[t * 64 + d4 + 0], z1 = zs[t * 64 + d4 + 1];
            float z2 = zs[t * 64 + d4 + 2], z3 = zs[t * 64 + d4 + 3];
            float dx = q.x - z0, dy = q.y - z1, dz = q.z - z2, dw = q.w - z3;
            s += dx*dx + dy*dy + dz*dz + dw*dw;
            *reinterpret_cast<float4*>(&zq_out[(size_t)row * NLAT + d4]) = q;
        }
        lred[t] = s;
    }
    __syncthreads();
    if (t == 0) {
        float s = 0.f;
        for (int q = 0; q < 64; q++) s += lred[q];
        partials[blockIdx.x] = s;
    }
}

// ---------------- fixup: fp32 re-decision for thin-gap rows ----------------
// 2048 blocks x 16 rows; local deterministic list (no atomics, no extra ws);
// batches of 4 rows share ONE hoisted W1 stream. Per-row math bitwise == R17.
__global__ __launch_bounds__(256)
void fixup_kernel(const float* __restrict__ x,  const float* __restrict__ w1,
                  const float* __restrict__ b1, const float* __restrict__ w2,
                  const float* __restrict__ b2, const float* __restrict__ cb,
                  const float* __restrict__ esq, const float* __restrict__ flags,
                  float* __restrict__ out) {
    float* zq_out  = out + ZQ_OFF;
    float* idx_out = out + IDX_OFF;
    __shared__ __align__(16) float xls[4][1024];
    __shared__ __align__(16) float hls[4][2048];
    __shared__ float zls[64];
    __shared__ float rb[256];
    __shared__ int   ri[256];
    __shared__ int   loclist[16];
    __shared__ int   nloc;
    const int t = threadIdx.x;
    const int brow = blockIdx.x * 16;

    if (t == 0) {
        int n = 0;
        for (int i = 0; i < 16; i++)
            if (flags[brow + i] < TAU) loclist[n++] = brow + i;
        nloc = n;
    }
    __syncthreads();
    const int n = nloc;
    if (n == 0) return;

    for (int b = 0; b < n; b += 4) {
        int nr = n - b; if (nr > 4) nr = 4;
        __syncthreads();   // prev batch's hls reads done before xls/hls overwrite
#pragma unroll
        for (int r = 0; r < 4; r++) {
            if (r < nr) {
                *reinterpret_cast<float4*>(&xls[r][t * 4]) =
                    *reinterpret_cast<const float4*>(&x[(size_t)loclist[b + r] * NIN + t * 4]);
            } else {
                *reinterpret_cast<float4*>(&xls[r][t * 4]) = make_float4(0.f, 0.f, 0.f, 0.f);
            }
        }
        __syncthreads();

        // hoisted GEMM1: one W1 pass serves the batch; per-row chains == R17
#pragma unroll
        for (int p = 0; p < 8; p++) {
            int j = t + 256 * p;
            float a0[4], a1[4], a2[4], a3[4];
#pragma unroll
            for (int r = 0; r < 4; r++) { a0[r] = 0.f; a1[r] = 0.f; a2[r] = 0.f; a3[r] = 0.f; }
            for (int k = 0; k < NIN; k += 4) {
                float w0 = w1[(size_t)(k + 0) * NHID + j];
                float w1v = w1[(size_t)(k + 1) * NHID + j];
                float w2v = w1[(size_t)(k + 2) * NHID + j];
                float w3v = w1[(size_t)(k + 3) * NHID + j];
#pragma unroll
                for (int r = 0; r < 4; r++) {
                    a0[r] += xls[r][k + 0] * w0;
                    a1[r] += xls[r][k + 1] * w1v;
                    a2[r] += xls[r][k + 2] * w2v;
                    a3[r] += xls[r][k + 3] * w3v;
                }
            }
            float bb = b1[j];
#pragma unroll
            for (int r = 0; r < 4; r++)
                hls[r][j] = fmaxf(((a0[r] + a1[r]) + (a2[r] + a3[r])) + bb, 0.f);
        }
        __syncthreads();

        for (int r = 0; r < nr; r++) {
            int row = loclist[b + r];
            if (t < 64) {
                float s0 = 0.f, s1 = 0.f, s2 = 0.f, s3 = 0.f;
                for (int k = 0; k < NHID; k += 4) {
                    s0 += hls[r][k + 0] * w2[(size_t)(k + 0) * NLAT + t];
                    s1 += hls[r][k + 1] * w2[(size_t)(k + 1) * NLAT + t];
                    s2 += hls[r][k + 2] * w2[(size_t)(k + 2) * NLAT + t];
                    s3 += hls[r][k + 3] * w2[(size_t)(k + 3) * NLAT + t];
                }
                zls[t] = ((s0 + s1) + (s2 + s3)) + b2[t];
            }
            __syncthreads();
            float zsq_ = 0.f;
            for (int d = 0; d < NLAT; d++) zsq_ += zls[d] * zls[d];
            float bv = FLTMAX; int bi = 0;
            for (int p = 0; p < 16; p++) {
                int c = t + 256 * p;
                float s0 = 0.f, s1 = 0.f, s2 = 0.f, s3 = 0.f;
                const float* cr = &cb[(size_t)c * NLAT];
                for (int d = 0; d < NLAT; d += 4) {
                    s0 += zls[d + 0] * cr[d + 0];
                    s1 += zls[d + 1] * cr[d + 1];
                    s2 += zls[d + 2] * cr[d + 2];
                    s3 += zls[d + 3] * cr[d + 3];
                }
                float d2 = (zsq_ - 2.f * ((s0 + s1) + (s2 + s3))) + esq[c];
                if (d2 < bv || (d2 == bv && c < bi)) { bv = d2; bi = c; }
            }
            rb[t] = bv; ri[t] = bi;
            __syncthreads();
            for (int s2r = 128; s2r >= 1; s2r >>= 1) {
                if (t < s2r) {
                    float ob = rb[t + s2r]; int oi = ri[t + s2r];
                    if (ob < rb[t] || (ob == rb[t] && oi < ri[t])) { rb[t] = ob; ri[t] = oi; }
                }
                __syncthreads();
            }
            if (t < 16) {
                int c = ri[0];
                if (t == 0) idx_out[row] = (float)c;
                float4 q = *reinterpret_cast<const float4*>(&cb[(size_t)c * NLAT + t * 4]);
                *reinterpret_cast<float4*>(&zq_out[(size_t)row * NLAT + t * 4]) = q;
            }
            __syncthreads();
        }
    }
}

// ---------------- loss ----------------
__global__ void loss_kernel(const float* __restrict__ partials, float* __restrict__ out_loss) {
    if (threadIdx.x == 0 && blockIdx.x == 0) {
        float s = 0.f;
        for (int i = 0; i < 512; i++) s += partials[i];
        *out_loss = (1.f + BETA) * s / (float)((size_t)NB * NLAT);
    }
}

// ---------------- MFMA decoder (verified, unchanged) ----------------
__global__ __launch_bounds__(256)
void dec_kernel(const float* __restrict__ out_base,
                const unsigned short* __restrict__ w1t,
                const unsigned short* __restrict__ w2t,
                const float* __restrict__ b1, const float* __restrict__ b2,
                float* __restrict__ xr) {
    const float* zq_in = out_base + ZQ_OFF;

    __shared__ __align__(16) unsigned short zqb[64 * 72];
    __shared__ __align__(16) unsigned short w1b[64 * 72];
    __shared__ __align__(16) unsigned short hdb[64 * 72];
    __shared__ __align__(16) unsigned short w2b[256 * 72];

    const int t = threadIdx.x;
    const int w = t >> 6, lane = t & 63, lo = lane & 15, hi = lane >> 4;
    const int rb = blockIdx.x >> 2, cbk = blockIdx.x & 3;
    const int brow = rb * 64, cbase = cbk * 256;

    {
        int row = t & 63, m = t >> 6;
        const float* src = &zq_in[(size_t)(brow + row) * NLAT + m * 16];
        unsigned int us[8];
#pragma unroll
        for (int j = 0; j < 4; j++) {
            float4 v = *reinterpret_cast<const float4*>(src + 4 * j);
            us[2*j]   = (unsigned int)f2bf(v.x) | ((unsigned int)f2bf(v.y) << 16);
            us[2*j+1] = (unsigned int)f2bf(v.z) | ((unsigned int)f2bf(v.w) << 16);
        }
        uint4 p0 = make_uint4(us[0], us[1], us[2], us[3]);
        uint4 p1 = make_uint4(us[4], us[5], us[6], us[7]);
        *reinterpret_cast<uint4*>(&zqb[row * 72 + m * 16 + 0]) = p0;
        *reinterpret_cast<uint4*>(&zqb[row * 72 + m * 16 + 8]) = p1;
    }

    v4f facc[4][4];
#pragma unroll
    for (int i = 0; i < 4; i++)
#pragma unroll
        for (int j = 0; j < 4; j++) facc[i][j] = (v4f){0.f, 0.f, 0.f, 0.f};

    for (int hc = 0; hc < NHID; hc += 64) {
        __syncthreads();
        {
            int cl = t & 63, mm = (t >> 6) * 2;
#pragma unroll
            for (int j = 0; j < 2; j++) {
                uint4 v = *reinterpret_cast<const uint4*>(&w1t[(size_t)(hc + cl) * 64 + (mm + j) * 8]);
                *reinterpret_cast<uint4*>(&w1b[cl * 72 + (mm + j) * 8]) = v;
            }
        }
        {
            const unsigned short* src = &w2t[(size_t)(cbase + t) * 2048 + hc];
#pragma unroll
            for (int j = 0; j < 8; j++) {
                uint4 v = *reinterpret_cast<const uint4*>(src + j * 8);
                *reinterpret_cast<uint4*>(&w2b[t * 72 + j * 8]) = v;
            }
        }
        __syncthreads();

        v8s a0 = *reinterpret_cast<const v8s*>(&zqb[(16 * w + lo) * 72 +  0 + hi * 8]);
        v8s a1 = *reinterpret_cast<const v8s*>(&zqb[(16 * w + lo) * 72 + 32 + hi * 8]);
#pragma unroll
        for (int ct = 0; ct < 4; ct++) {
            v8s bb0 = *reinterpret_cast<const v8s*>(&w1b[(16 * ct + lo) * 72 +  0 + hi * 8]);
            v8s bb1 = *reinterpret_cast<const v8s*>(&w1b[(16 * ct + lo) * 72 + 32 + hi * 8]);
            v4f acc = (v4f){0.f, 0.f, 0.f, 0.f};
            acc = __builtin_amdgcn_mfma_f32_16x16x32_bf16(a0, bb0, acc, 0, 0, 0);
            acc = __builtin_amdgcn_mfma_f32_16x16x32_bf16(a1, bb1, acc, 0, 0, 0);
            float bias = b1[hc + 16 * ct + lo];
#pragma unroll
            for (int r = 0; r < 4; r++) {
                float hv = fmaxf(acc[r] + bias, 0.f);
                hdb[(16 * w + 4 * hi + r) * 72 + 16 * ct + lo] = f2bf(hv);
            }
        }
        __syncthreads();

#pragma unroll
        for (int kk = 0; kk < 2; kk++) {
            v8s af[4];
#pragma unroll
            for (int rt = 0; rt < 4; rt++)
                af[rt] = *reinterpret_cast<const v8s*>(&hdb[(16 * rt + lo) * 72 + kk * 32 + hi * 8]);
#pragma unroll
            for (int ctl = 0; ctl < 4; ctl++) {
                v8s bf_ = *reinterpret_cast<const v8s*>(&w2b[(64 * w + 16 * ctl + lo) * 72 + kk * 32 + hi * 8]);
#pragma unroll
                for (int rt = 0; rt < 4; rt++)
                    facc[rt][ctl] = __builtin_amdgcn_mfma_f32_16x16x32_bf16(af[rt], bf_, facc[rt][ctl], 0, 0, 0);
            }
        }
    }

#pragma unroll
    for (int ctl = 0; ctl < 4; ctl++) {
        int col = cbase + 64 * w + 16 * ctl + lo;
        float bias = b2[col];
#pragma unroll
        for (int rt = 0; rt < 4; rt++) {
#pragma unroll
            for (int r = 0; r < 4; r++) {
                int row = brow + 16 * rt + 4 * hi + r;
                xr[(size_t)row * NIN + col] = facc[rt][ctl][r] + bias;
            }
        }
    }
}

extern "C" void kernel_launch(void* const* d_in, const int* in_sizes, int n_in,
                              void* d_out, int out_size, void* d_ws, size_t ws_size,
                              hipStream_t stream) {
    (void)in_sizes; (void)n_in; (void)out_size; (void)ws_size;
    const float* x   = (const float*)d_in[0];
    const float* ew1 = (const float*)d_in[1];
    const float* eb1 = (const float*)d_in[2];
    const float* ew2 = (const float*)d_in[3];
    const float* eb2 = (const float*)d_in[4];
    const float* cb  = (const float*)d_in[5];
    const float* dw1 = (const float*)d_in[6];
    const float* db1 = (const float*)d_in[7];
    const float* dw2 = (const float*)d_in[8];
    const float* db2 = (const float*)d_in[9];

    float* out  = (float*)d_out;
    float* part = (float*)d_ws + PART_WS_F;
    float* esq  = (float*)((char*)d_ws + ESQ_WS_B);
    unsigned short* w1t  = (unsigned short*)((char*)d_ws + W1T_WS_B);
    unsigned short* w2t  = (unsigned short*)((char*)d_ws + W2T_WS_B);
    unsigned short* w1hT = (unsigned short*)((char*)d_ws + W1HT_WS_B);
    unsigned short* w1mT = (unsigned short*)((char*)d_ws + W1MT_WS_B);
    unsigned short* w1lT = (unsigned short*)((char*)d_ws + W1LT_WS_B);
    float* flags = (float*)((char*)d_ws + FLAGS_WS_B);

    esq_kernel<<<NEMB / 256, 256, 0, stream>>>(cb, esq);
    prep_w1t<<<512, 256, 0, stream>>>(dw1, w1t);
    prep_w2t<<<8192, 256, 0, stream>>>(dw2, w2t);
    prep_w1split<<<512, 256, 0, stream>>>(ew1, w1hT, w1mT, w1lT);
    encvq_kernel<<<NB / 64, 512, 0, stream>>>(x, w1hT, w1mT, w1lT, eb1, ew2, eb2,
                                              cb, esq, out, part, flags);
    fixup_kernel<<<NB / 16, 256, 0, stream>>>(x, ew1, eb1, ew2, eb2, cb, esq, flags, out);
    loss_kernel<<<1, 64, 0, stream>>>(part, out + LOSS_OFF);
    dec_kernel<<<(NB / 64) * 4, 256, 0, stream>>>(out, w1t, w2t, db1, db2, out + XR_OFF);
}

// Round 20
// 2153.024 us; speedup vs baseline: 1.0670x; 1.0670x over previous
//
#include <hip/hip_runtime.h>
#include <hip/hip_bf16.h>

#define NB    32768
#define NIN   1024
#define NHID  2048
#define NLAT  64
#define NEMB  4096
#define BETA  0.25f
#define TAU   0.004f

#define FLTMAX 3.402823466e+38f

// ---- output layout (FLOAT32 elements) ----
#define XR_OFF   0
#define ZE_OFF   33554432
#define ZQ_OFF   35651584
#define IDX_OFF  37748736
#define LOSS_OFF 37781504

// ---- ws layout (bytes) — IDENTICAL to the R17 proven map (max 17,190,912) ----
#define PART_WS_F   0          // 512 f32 loss partials
#define ESQ_WS_B    4096       // 4096 f32
#define W1T_WS_B    20480      // dec w1t bf16 [2048][64]
#define W2T_WS_B    282624     // dec w2t bf16 [1024][2048] -> ends 4476928
#define W1HT_WS_B   4476928    // enc w1 split hi  bf16 [2048 h][1024 k]
#define W1MT_WS_B   8671232    // enc w1 split mid
#define W1LT_WS_B   12865536   // enc w1 split lo  -> ends 17059840
#define FLAGS_WS_B  17059840   // 32768 f32 gaps -> ends 17190912

typedef short v8s __attribute__((ext_vector_type(8)));
typedef float v4f __attribute__((ext_vector_type(4)));

static __device__ __forceinline__ unsigned short f2bf(float f) {
    union { __hip_bfloat16 h; unsigned short u; } v;
    v.h = __float2bfloat16(f);
    return v.u;
}

// exact truncation split: v == bh + bm + bl (as bf16-representable f32s)
static __device__ __forceinline__ void split3(float v, unsigned short& h,
                                              unsigned short& m, unsigned short& l) {
    unsigned int u = __float_as_uint(v);
    h = (unsigned short)(u >> 16);
    float r1 = v - __uint_as_float(u & 0xFFFF0000u);
    unsigned int u1 = __float_as_uint(r1);
    m = (unsigned short)(u1 >> 16);
    float r2 = r1 - __uint_as_float(u1 & 0xFFFF0000u);
    l = (unsigned short)(__float_as_uint(r2) >> 16);
}

// ---------------- codebook norms ----------------
__global__ void esq_kernel(const float* __restrict__ cb, float* __restrict__ esq) {
    int c = blockIdx.x * 256 + threadIdx.x;
    float s = 0.f;
#pragma unroll
    for (int d4 = 0; d4 < NLAT; d4 += 4) {
        float4 v = *reinterpret_cast<const float4*>(&cb[(size_t)c * NLAT + d4]);
        s += v.x * v.x; s += v.y * v.y; s += v.z * v.z; s += v.w * v.w;
    }
    esq[c] = s;
}

// ---------------- prep: decoder weights ----------------
__global__ void prep_w1t(const float* __restrict__ dw1, unsigned short* __restrict__ w1t) {
    int idx = blockIdx.x * 256 + threadIdx.x;
    int l = idx >> 11, h = idx & 2047;
    w1t[h * 64 + l] = f2bf(dw1[l * 2048 + h]);
}
__global__ void prep_w2t(const float* __restrict__ dw2, unsigned short* __restrict__ w2t) {
    int idx = blockIdx.x * 256 + threadIdx.x;
    int k = idx >> 10, c = idx & 1023;
    w2t[(size_t)c * 2048 + k] = f2bf(dw2[(size_t)k * 1024 + c]);
}

// ---------------- prep: encoder w1 transpose + 3-way bf16 split ----------------
__global__ void prep_w1split(const float* __restrict__ w1,
                             unsigned short* __restrict__ w1hT,
                             unsigned short* __restrict__ w1mT,
                             unsigned short* __restrict__ w1lT) {
    __shared__ __align__(16) float tile[64][68];
    int kb = blockIdx.x & 15, hb = blockIdx.x >> 4;
    int k0 = kb * 64, h0 = hb * 64;
    int r = threadIdx.x >> 4, c4 = (threadIdx.x & 15) * 4;
#pragma unroll
    for (int i = 0; i < 4; i++) {
        int rr = r + 16 * i;
        float4 v = *reinterpret_cast<const float4*>(&w1[(size_t)(k0 + rr) * NHID + h0 + c4]);
        tile[rr][c4 + 0] = v.x; tile[rr][c4 + 1] = v.y;
        tile[rr][c4 + 2] = v.z; tile[rr][c4 + 3] = v.w;
    }
    __syncthreads();
#pragma unroll
    for (int i = 0; i < 4; i++) {
        int hh = r + 16 * i;
        unsigned short sh[4], sm[4], sl[4];
#pragma unroll
        for (int j = 0; j < 4; j++) {
            split3(tile[c4 + j][hh], sh[j], sm[j], sl[j]);
        }
        size_t addr = (size_t)(h0 + hh) * 1024 + k0 + c4;
        *reinterpret_cast<ushort4*>(&w1hT[addr]) = make_ushort4(sh[0], sh[1], sh[2], sh[3]);
        *reinterpret_cast<ushort4*>(&w1mT[addr]) = make_ushort4(sm[0], sm[1], sm[2], sm[3]);
        *reinterpret_cast<ushort4*>(&w1lT[addr]) = make_ushort4(sl[0], sl[1], sl[2], sl[3]);
    }
}

// ---------------- fused encoder (MFMA 3-split) + GEMM2 (fp32, single-loop) + VQ ----------------
// Numerics bitwise == R17: h values identical (same acc+bias, relu), zacc FMA
// sequence identical (global k ascending 0..255 per jc), VQ/z path verbatim.
__global__ __launch_bounds__(512)
void encvq_kernel(const float* __restrict__ x,
                  const unsigned short* __restrict__ w1hT,
                  const unsigned short* __restrict__ w1mT,
                  const unsigned short* __restrict__ w1lT,
                  const float* __restrict__ b1, const float* __restrict__ w2,
                  const float* __restrict__ b2, const float* __restrict__ cb,
                  const float* __restrict__ esq,
                  float* __restrict__ out, float* __restrict__ partials,
                  float* __restrict__ flags) {
    float* ze_out  = out + ZE_OFF;
    float* zq_out  = out + ZQ_OFF;
    float* idx_out = out + IDX_OFF;

    static __shared__ __align__(16) unsigned char smem[76800];
    unsigned short* xh  = (unsigned short*)(smem);
    unsigned short* xm  = (unsigned short*)(smem + 5120);
    unsigned short* xl  = (unsigned short*)(smem + 10240);
    unsigned short* bsh = (unsigned short*)(smem + 15360);
    unsigned short* bsm = (unsigned short*)(smem + 35840);
    unsigned short* bsl = (unsigned short*)(smem + 56320);
    float* hbig = (float*)(smem);            // [64][260] f32 = 66560 B (aliases x*/bs*)
    float* zs  = (float*)(smem);             // VQ: [64][64] f32 (R17 map)
    float* cbs = (float*)(smem + 16384);     // VQ: [128][68] f32 (R17 map)
    __shared__ int   ridx2[64];
    __shared__ float zsq[64];
    __shared__ float lred[64];

    const int t = threadIdx.x;
    const int rg = t >> 5, cg = t & 31;
    const int wv = t >> 6, lane = t & 63;
    const int wr = wv >> 2, wc = wv & 3;
    const int lo = lane & 15, hi = lane >> 4;
    const int brow = blockIdx.x * 64;

    float2 zacc[4];
#pragma unroll
    for (int i = 0; i < 4; i++) zacc[i] = make_float2(0.f, 0.f);

    for (int jc = 0; jc < NHID; jc += 256) {
        // -------- GEMM1 (MFMA, R17 verbatim) --------
        v4f acc[2][4];
#pragma unroll
        for (int rt = 0; rt < 2; rt++)
#pragma unroll
            for (int ct = 0; ct < 4; ct++) acc[rt][ct] = (v4f){0.f, 0.f, 0.f, 0.f};

        for (int kc = 0; kc < NIN; kc += 32) {
            __syncthreads();   // prev frag reads / prev-jc hbig (GEMM2) reads done
            {
                int row = t >> 3, seg = t & 7;
                float4 v = *reinterpret_cast<const float4*>(
                    &x[(size_t)(brow + row) * NIN + kc + seg * 4]);
                unsigned short sh[4], sm[4], sl[4];
                split3(v.x, sh[0], sm[0], sl[0]);
                split3(v.y, sh[1], sm[1], sl[1]);
                split3(v.z, sh[2], sm[2], sl[2]);
                split3(v.w, sh[3], sm[3], sl[3]);
                int a = row * 40 + seg * 4;
                *reinterpret_cast<ushort4*>(&xh[a]) = make_ushort4(sh[0], sh[1], sh[2], sh[3]);
                *reinterpret_cast<ushort4*>(&xm[a]) = make_ushort4(sm[0], sm[1], sm[2], sm[3]);
                *reinterpret_cast<ushort4*>(&xl[a]) = make_ushort4(sl[0], sl[1], sl[2], sl[3]);
            }
#pragma unroll
            for (int jj = 0; jj < 2; jj++) {
                int col = (t >> 2) + 128 * jj, segb = t & 3;
                size_t src = (size_t)(jc + col) * 1024 + kc + segb * 8;
                int dst = col * 40 + segb * 8;
                *reinterpret_cast<uint4*>(&bsh[dst]) = *reinterpret_cast<const uint4*>(&w1hT[src]);
                *reinterpret_cast<uint4*>(&bsm[dst]) = *reinterpret_cast<const uint4*>(&w1mT[src]);
                *reinterpret_cast<uint4*>(&bsl[dst]) = *reinterpret_cast<const uint4*>(&w1lT[src]);
            }
            __syncthreads();

            v8s Ah[2], Am[2], Al[2];
#pragma unroll
            for (int rt = 0; rt < 2; rt++) {
                int ra = (32 * wr + 16 * rt + lo) * 40 + hi * 8;
                Ah[rt] = *reinterpret_cast<const v8s*>(&xh[ra]);
                Am[rt] = *reinterpret_cast<const v8s*>(&xm[ra]);
                Al[rt] = *reinterpret_cast<const v8s*>(&xl[ra]);
            }
#pragma unroll
            for (int ct = 0; ct < 4; ct++) {
                int ba = (64 * wc + 16 * ct + lo) * 40 + hi * 8;
                v8s Bh = *reinterpret_cast<const v8s*>(&bsh[ba]);
                v8s Bm = *reinterpret_cast<const v8s*>(&bsm[ba]);
                v8s Bl = *reinterpret_cast<const v8s*>(&bsl[ba]);
#pragma unroll
                for (int rt = 0; rt < 2; rt++) {
                    acc[rt][ct] = __builtin_amdgcn_mfma_f32_16x16x32_bf16(Ah[rt], Bh, acc[rt][ct], 0, 0, 0);
                    acc[rt][ct] = __builtin_amdgcn_mfma_f32_16x16x32_bf16(Ah[rt], Bm, acc[rt][ct], 0, 0, 0);
                    acc[rt][ct] = __builtin_amdgcn_mfma_f32_16x16x32_bf16(Am[rt], Bh, acc[rt][ct], 0, 0, 0);
                    acc[rt][ct] = __builtin_amdgcn_mfma_f32_16x16x32_bf16(Ah[rt], Bl, acc[rt][ct], 0, 0, 0);
                    acc[rt][ct] = __builtin_amdgcn_mfma_f32_16x16x32_bf16(Al[rt], Bh, acc[rt][ct], 0, 0, 0);
                    acc[rt][ct] = __builtin_amdgcn_mfma_f32_16x16x32_bf16(Am[rt], Bm, acc[rt][ct], 0, 0, 0);
                }
            }
        }

        // -------- h handoff: single full-tile write (values bitwise == R17) --------
        __syncthreads();   // all frag reads of bs* done before hbig overwrites
#pragma unroll
        for (int ct2 = 0; ct2 < 4; ct2++) {
            float bias = b1[jc + 64 * wc + 16 * ct2 + lo];
#pragma unroll
            for (int rt = 0; rt < 2; rt++) {
#pragma unroll
                for (int r = 0; r < 4; r++) {
                    int rl = 32 * wr + 16 * rt + 4 * hi + r;
                    hbig[rl * 260 + 64 * wc + 16 * ct2 + lo] =
                        fmaxf(acc[rt][ct2][r] + bias, 0.f);
                }
            }
        }
        __syncthreads();

        // -------- GEMM2: single 256-k loop, w2 direct from global (L1-broadcast).
        // FMA sequence identical to R17 (global k ascending). --------
#pragma unroll 4
        for (int kk = 0; kk < 256; kk++) {
            float2 wvv = *reinterpret_cast<const float2*>(&w2[(size_t)(jc + kk) * NLAT + cg * 2]);
#pragma unroll
            for (int i = 0; i < 4; i++) {
                float hv = hbig[(rg + 16 * i) * 260 + kk];   // broadcast per rg group
                zacc[i].x += hv * wvv.x;
                zacc[i].y += hv * wvv.y;
            }
        }
    }

    __syncthreads();   // hbig reads done before zs (alias) writes
    {
        float2 b2v = *reinterpret_cast<const float2*>(&b2[cg * 2]);
#pragma unroll
        for (int i = 0; i < 4; i++) {
            int row = brow + rg + 16 * i;
            float2 z = make_float2(zacc[i].x + b2v.x, zacc[i].y + b2v.y);
            *reinterpret_cast<float2*>(&zs[(rg + 16 * i) * 64 + cg * 2]) = z;
            *reinterpret_cast<float2*>(&ze_out[(size_t)row * NLAT + cg * 2]) = z;
        }
    }
    __syncthreads();

    // ---------------- VQ with top-2 tracking (R17 verbatim) ----------------
    if (t < 64) {
        float s = 0.f;
#pragma unroll 16
        for (int d = 0; d < 64; d++) { float v = zs[t * 64 + d]; s += v * v; }
        zsq[t] = s;
    }
    __syncthreads();
    float zr[4];
#pragma unroll
    for (int i = 0; i < 4; i++) zr[i] = zsq[rg + 16 * i];

    float best[4], b2nd[4]; int bidx[4];
#pragma unroll
    for (int i = 0; i < 4; i++) { best[i] = FLTMAX; b2nd[i] = FLTMAX; bidx[i] = 0; }

    for (int cc = 0; cc < NEMB; cc += 128) {
        __syncthreads();
#pragma unroll
        for (int jj = 0; jj < 4; jj++) {
            int id = t + 512 * jj;
            int r = id >> 4, c4 = (id & 15) * 4;
            *reinterpret_cast<float4*>(&cbs[r * 68 + c4]) =
                *reinterpret_cast<const float4*>(&cb[(size_t)(cc + r) * NLAT + c4]);
        }
        __syncthreads();
        float dot[4][4];
#pragma unroll
        for (int i = 0; i < 4; i++)
#pragma unroll
            for (int j = 0; j < 4; j++) dot[i][j] = 0.f;
#pragma unroll 2
        for (int d4 = 0; d4 < 64; d4 += 4) {
            float4 zv[4];
#pragma unroll
            for (int i = 0; i < 4; i++)
                zv[i] = *reinterpret_cast<float4*>(&zs[(rg + 16 * i) * 64 + d4]);
#pragma unroll
            for (int j = 0; j < 4; j++) {
                float4 cv = *reinterpret_cast<float4*>(&cbs[(cg + 32 * j) * 68 + d4]);
#pragma unroll
                for (int i = 0; i < 4; i++) {
                    dot[i][j] += zv[i].x*cv.x + zv[i].y*cv.y + zv[i].z*cv.z + zv[i].w*cv.w;
                }
            }
        }
#pragma unroll
        for (int j = 0; j < 4; j++) {
            int cl = cg + 32 * j;
            float eq = esq[cc + cl];
#pragma unroll
            for (int i = 0; i < 4; i++) {
                float d2 = (zr[i] - 2.f * dot[i][j]) + eq;
                int c = cc + cl;
                if (d2 < best[i] || (d2 == best[i] && c < bidx[i])) {
                    b2nd[i] = fminf(best[i], b2nd[i]);
                    best[i] = d2; bidx[i] = c;
                } else {
                    b2nd[i] = fminf(b2nd[i], d2);
                }
            }
        }
    }
#pragma unroll
    for (int off = 16; off >= 1; off >>= 1) {
#pragma unroll
        for (int i = 0; i < 4; i++) {
            float ob  = __shfl_xor(best[i], off, 64);
            int   oi  = __shfl_xor(bidx[i], off, 64);
            float ob2 = __shfl_xor(b2nd[i], off, 64);
            if (ob < best[i] || (ob == best[i] && oi < bidx[i])) {
                b2nd[i] = fminf(best[i], ob2);
                best[i] = ob; bidx[i] = oi;
            } else {
                b2nd[i] = fminf(b2nd[i], ob);
            }
        }
    }
    if (cg == 0) {
#pragma unroll
        for (int i = 0; i < 4; i++) {
            ridx2[rg + 16 * i] = bidx[i];
            flags[brow + rg + 16 * i] = b2nd[i] - best[i];
        }
    }
    __syncthreads();
    if (t < 64) {
        int c = ridx2[t] & (NEMB - 1);
        int row = brow + t;
        idx_out[row] = (float)c;
        float s = 0.f;
#pragma unroll
        for (int d4 = 0; d4 < 64; d4 += 4) {
            float4 q = *reinterpret_cast<const float4*>(&cb[(size_t)c * NLAT + d4]);
            float z0 = zs[t * 64 + d4 + 0], z1 = zs[t * 64 + d4 + 1];
            float z2 = zs[t * 64 + d4 + 2], z3 = zs[t * 64 + d4 + 3];
            float dx = q.x - z0, dy = q.y - z1, dz = q.z - z2, dw = q.w - z3;
            s += dx*dx + dy*dy + dz*dz + dw*dw;
            *reinterpret_cast<float4*>(&zq_out[(size_t)row * NLAT + d4]) = q;
        }
        lred[t] = s;
    }
    __syncthreads();
    if (t == 0) {
        float s = 0.f;
        for (int q = 0; q < 64; q++) s += lred[q];
        partials[blockIdx.x] = s;
    }
}

// ---------------- fixup: fp32 re-decision for thin-gap rows (R17 verbatim) ----------------
__global__ __launch_bounds__(256)
void fixup_kernel(const float* __restrict__ x,  const float* __restrict__ w1,
                  const float* __restrict__ b1, const float* __restrict__ w2,
                  const float* __restrict__ b2, const float* __restrict__ cb,
                  const float* __restrict__ esq, const float* __restrict__ flags,
                  float* __restrict__ out) {
    float* zq_out  = out + ZQ_OFF;
    float* idx_out = out + IDX_OFF;
    __shared__ __align__(16) float xls[1024];
    __shared__ __align__(16) float hls[2048];
    __shared__ float zls[64];
    __shared__ float rb[256];
    __shared__ int   ri[256];
    __shared__ int   rowflags[16];
    const int t = threadIdx.x;
    const int brow = blockIdx.x * 16;

    if (t < 16) rowflags[t] = (flags[brow + t] < TAU) ? 1 : 0;
    __syncthreads();

    for (int rr = 0; rr < 16; rr++) {
        if (!rowflags[rr]) continue;                      // uniform branch
        int row = brow + rr;
        *reinterpret_cast<float4*>(&xls[t * 4]) =
            *reinterpret_cast<const float4*>(&x[(size_t)row * NIN + t * 4]);
        __syncthreads();
#pragma unroll
        for (int p = 0; p < 8; p++) {
            int j = t + 256 * p;
            float s0 = 0.f, s1 = 0.f, s2 = 0.f, s3 = 0.f;
            for (int k = 0; k < NIN; k += 4) {
                s0 += xls[k + 0] * w1[(size_t)(k + 0) * NHID + j];
                s1 += xls[k + 1] * w1[(size_t)(k + 1) * NHID + j];
                s2 += xls[k + 2] * w1[(size_t)(k + 2) * NHID + j];
                s3 += xls[k + 3] * w1[(size_t)(k + 3) * NHID + j];
            }
            hls[j] = fmaxf(((s0 + s1) + (s2 + s3)) + b1[j], 0.f);
        }
        __syncthreads();
        if (t < 64) {
            float s0 = 0.f, s1 = 0.f, s2 = 0.f, s3 = 0.f;
            for (int k = 0; k < NHID; k += 4) {
                s0 += hls[k + 0] * w2[(size_t)(k + 0) * NLAT + t];
                s1 += hls[k + 1] * w2[(size_t)(k + 1) * NLAT + t];
                s2 += hls[k + 2] * w2[(size_t)(k + 2) * NLAT + t];
                s3 += hls[k + 3] * w2[(size_t)(k + 3) * NLAT + t];
            }
            zls[t] = ((s0 + s1) + (s2 + s3)) + b2[t];
        }
        __syncthreads();
        float zsq_ = 0.f;
        for (int d = 0; d < NLAT; d++) zsq_ += zls[d] * zls[d];
        float bv = FLTMAX; int bi = 0;
        for (int p = 0; p < 16; p++) {
            int c = t + 256 * p;                          // ascending per thread
            float s0 = 0.f, s1 = 0.f, s2 = 0.f, s3 = 0.f;
            const float* cr = &cb[(size_t)c * NLAT];
            for (int d = 0; d < NLAT; d += 4) {
                s0 += zls[d + 0] * cr[d + 0];
                s1 += zls[d + 1] * cr[d + 1];
                s2 += zls[d + 2] * cr[d + 2];
                s3 += zls[d + 3] * cr[d + 3];
            }
            float d2 = (zsq_ - 2.f * ((s0 + s1) + (s2 + s3))) + esq[c];
            if (d2 < bv || (d2 == bv && c < bi)) { bv = d2; bi = c; }
        }
        rb[t] = bv; ri[t] = bi;
        __syncthreads();
        for (int s2r = 128; s2r >= 1; s2r >>= 1) {
            if (t < s2r) {
                float ob = rb[t + s2r]; int oi = ri[t + s2r];
                if (ob < rb[t] || (ob == rb[t] && oi < ri[t])) { rb[t] = ob; ri[t] = oi; }
            }
            __syncthreads();
        }
        if (t < 16) {
            int c = ri[0];
            if (t == 0) idx_out[row] = (float)c;
            float4 q = *reinterpret_cast<const float4*>(&cb[(size_t)c * NLAT + t * 4]);
            *reinterpret_cast<float4*>(&zq_out[(size_t)row * NLAT + t * 4]) = q;
        }
        __syncthreads();
    }
}

// ---------------- loss ----------------
__global__ void loss_kernel(const float* __restrict__ partials, float* __restrict__ out_loss) {
    if (threadIdx.x == 0 && blockIdx.x == 0) {
        float s = 0.f;
        for (int i = 0; i < 512; i++) s += partials[i];
        *out_loss = (1.f + BETA) * s / (float)((size_t)NB * NLAT);
    }
}

// ---------------- MFMA decoder (verified, unchanged) ----------------
__global__ __launch_bounds__(256)
void dec_kernel(const float* __restrict__ out_base,
                const unsigned short* __restrict__ w1t,
                const unsigned short* __restrict__ w2t,
                const float* __restrict__ b1, const float* __restrict__ b2,
                float* __restrict__ xr) {
    const float* zq_in = out_base + ZQ_OFF;

    __shared__ __align__(16) unsigned short zqb[64 * 72];
    __shared__ __align__(16) unsigned short w1b[64 * 72];
    __shared__ __align__(16) unsigned short hdb[64 * 72];
    __shared__ __align__(16) unsigned short w2b[256 * 72];

    const int t = threadIdx.x;
    const int w = t >> 6, lane = t & 63, lo = lane & 15, hi = lane >> 4;
    const int rb = blockIdx.x >> 2, cbk = blockIdx.x & 3;
    const int brow = rb * 64, cbase = cbk * 256;

    {
        int row = t & 63, m = t >> 6;
        const float* src = &zq_in[(size_t)(brow + row) * NLAT + m * 16];
        unsigned int us[8];
#pragma unroll
        for (int j = 0; j < 4; j++) {
            float4 v = *reinterpret_cast<const float4*>(src + 4 * j);
            us[2*j]   = (unsigned int)f2bf(v.x) | ((unsigned int)f2bf(v.y) << 16);
            us[2*j+1] = (unsigned int)f2bf(v.z) | ((unsigned int)f2bf(v.w) << 16);
        }
        uint4 p0 = make_uint4(us[0], us[1], us[2], us[3]);
        uint4 p1 = make_uint4(us[4], us[5], us[6], us[7]);
        *reinterpret_cast<uint4*>(&zqb[row * 72 + m * 16 + 0]) = p0;
        *reinterpret_cast<uint4*>(&zqb[row * 72 + m * 16 + 8]) = p1;
    }

    v4f facc[4][4];
#pragma unroll
    for (int i = 0; i < 4; i++)
#pragma unroll
        for (int j = 0; j < 4; j++) facc[i][j] = (v4f){0.f, 0.f, 0.f, 0.f};

    for (int hc = 0; hc < NHID; hc += 64) {
        __syncthreads();
        {
            int cl = t & 63, mm = (t >> 6) * 2;
#pragma unroll
            for (int j = 0; j < 2; j++) {
                uint4 v = *reinterpret_cast<const uint4*>(&w1t[(size_t)(hc + cl) * 64 + (mm + j) * 8]);
                *reinterpret_cast<uint4*>(&w1b[cl * 72 + (mm + j) * 8]) = v;
            }
        }
        {
            const unsigned short* src = &w2t[(size_t)(cbase + t) * 2048 + hc];
#pragma unroll
            for (int j = 0; j < 8; j++) {
                uint4 v = *reinterpret_cast<const uint4*>(src + j * 8);
                *reinterpret_cast<uint4*>(&w2b[t * 72 + j * 8]) = v;
            }
        }
        __syncthreads();

        v8s a0 = *reinterpret_cast<const v8s*>(&zqb[(16 * w + lo) * 72 +  0 + hi * 8]);
        v8s a1 = *reinterpret_cast<const v8s*>(&zqb[(16 * w + lo) * 72 + 32 + hi * 8]);
#pragma unroll
        for (int ct = 0; ct < 4; ct++) {
            v8s bb0 = *reinterpret_cast<const v8s*>(&w1b[(16 * ct + lo) * 72 +  0 + hi * 8]);
            v8s bb1 = *reinterpret_cast<const v8s*>(&w1b[(16 * ct + lo) * 72 + 32 + hi * 8]);
            v4f acc = (v4f){0.f, 0.f, 0.f, 0.f};
            acc = __builtin_amdgcn_mfma_f32_16x16x32_bf16(a0, bb0, acc, 0, 0, 0);
            acc = __builtin_amdgcn_mfma_f32_16x16x32_bf16(a1, bb1, acc, 0, 0, 0);
            float bias = b1[hc + 16 * ct + lo];
#pragma unroll
            for (int r = 0; r < 4; r++) {
                float hv = fmaxf(acc[r] + bias, 0.f);
                hdb[(16 * w + 4 * hi + r) * 72 + 16 * ct + lo] = f2bf(hv);
            }
        }
        __syncthreads();

#pragma unroll
        for (int kk = 0; kk < 2; kk++) {
            v8s af[4];
#pragma unroll
            for (int rt = 0; rt < 4; rt++)
                af[rt] = *reinterpret_cast<const v8s*>(&hdb[(16 * rt + lo) * 72 + kk * 32 + hi * 8]);
#pragma unroll
            for (int ctl = 0; ctl < 4; ctl++) {
                v8s bf_ = *reinterpret_cast<const v8s*>(&w2b[(64 * w + 16 * ctl + lo) * 72 + kk * 32 + hi * 8]);
#pragma unroll
                for (int rt = 0; rt < 4; rt++)
                    facc[rt][ctl] = __builtin_amdgcn_mfma_f32_16x16x32_bf16(af[rt], bf_, facc[rt][ctl], 0, 0, 0);
            }
        }
    }

#pragma unroll
    for (int ctl = 0; ctl < 4; ctl++) {
        int col = cbase + 64 * w + 16 * ctl + lo;
        float bias = b2[col];
#pragma unroll
        for (int rt = 0; rt < 4; rt++) {
#pragma unroll
            for (int r = 0; r < 4; r++) {
                int row = brow + 16 * rt + 4 * hi + r;
                xr[(size_t)row * NIN + col] = facc[rt][ctl][r] + bias;
            }
        }
    }
}

extern "C" void kernel_launch(void* const* d_in, const int* in_sizes, int n_in,
                              void* d_out, int out_size, void* d_ws, size_t ws_size,
                              hipStream_t stream) {
    (void)in_sizes; (void)n_in; (void)out_size; (void)ws_size;
    const float* x   = (const float*)d_in[0];
    const float* ew1 = (const float*)d_in[1];
    const float* eb1 = (const float*)d_in[2];
    const float* ew2 = (const float*)d_in[3];
    const float* eb2 = (const float*)d_in[4];
    const float* cb  = (const float*)d_in[5];
    const float* dw1 = (const float*)d_in[6];
    const float* db1 = (const float*)d_in[7];
    const float* dw2 = (const float*)d_in[8];
    const float* db2 = (const float*)d_in[9];

    float* out  = (float*)d_out;
    float* part = (float*)d_ws + PART_WS_F;
    float* esq  = (float*)((char*)d_ws + ESQ_WS_B);
    unsigned short* w1t  = (unsigned short*)((char*)d_ws + W1T_WS_B);
    unsigned short* w2t  = (unsigned short*)((char*)d_ws + W2T_WS_B);
    unsigned short* w1hT = (unsigned short*)((char*)d_ws + W1HT_WS_B);
    unsigned short* w1mT = (unsigned short*)((char*)d_ws + W1MT_WS_B);
    unsigned short* w1lT = (unsigned short*)((char*)d_ws + W1LT_WS_B);
    float* flags = (float*)((char*)d_ws + FLAGS_WS_B);

    esq_kernel<<<NEMB / 256, 256, 0, stream>>>(cb, esq);
    prep_w1t<<<512, 256, 0, stream>>>(dw1, w1t);
    prep_w2t<<<8192, 256, 0, stream>>>(dw2, w2t);
    prep_w1split<<<512, 256, 0, stream>>>(ew1, w1hT, w1mT, w1lT);
    encvq_kernel<<<NB / 64, 512, 0, stream>>>(x, w1hT, w1mT, w1lT, eb1, ew2, eb2,
                                              cb, esq, out, part, flags);
    fixup_kernel<<<NB / 16, 256, 0, stream>>>(x, ew1, eb1, ew2, eb2, cb, esq, flags, out);
    loss_kernel<<<1, 64, 0, stream>>>(part, out + LOSS_OFF);
    dec_kernel<<<(NB / 64) * 4, 256, 0, stream>>>(out, w1t, w2t, db1, db2, out + XR_OFF);
}

// Round 22
// 2099.864 us; speedup vs baseline: 1.0940x; 1.0253x over previous
//
#include <hip/hip_runtime.h>
#include <hip/hip_bf16.h>

#define NB    32768
#define NIN   1024
#define NHID  2048
#define NLAT  64
#define NEMB  4096
#define BETA  0.25f
#define TAU   0.004f

#define FLTMAX 3.402823466e+38f

// ---- output layout (FLOAT32 elements) ----
#define XR_OFF   0
#define ZE_OFF   33554432
#define ZQ_OFF   35651584
#define IDX_OFF  37748736
#define LOSS_OFF 37781504

// ---- ws layout (bytes) — R17 proven map (max 17,190,912) ----
#define PART_WS_F   0          // 512 f32 loss partials
#define ESQ_WS_B    4096       // 4096 f32
#define W1T_WS_B    20480      // dec w1t bf16 [2048][64]
#define W2T_WS_B    282624     // dec w2t bf16 [1024][2048] -> ends 4476928
#define W1HT_WS_B   4476928    // enc w1 split hi  bf16 [2048 h][1024 k]
#define W1MT_WS_B   8671232    // enc w1 split mid
#define W1LT_WS_B   12865536   // enc w1 split lo  -> ends 17059840
#define FLAGS_WS_B  17059840   // 32768 f32 gaps -> ends 17190912

typedef short v8s __attribute__((ext_vector_type(8)));
typedef float v4f __attribute__((ext_vector_type(4)));

static __device__ __forceinline__ unsigned short f2bf(float f) {
    union { __hip_bfloat16 h; unsigned short u; } v;
    v.h = __float2bfloat16(f);
    return v.u;
}

// exact truncation split: v == bh + bm + bl (as bf16-representable f32s)
static __device__ __forceinline__ void split3(float v, unsigned short& h,
                                              unsigned short& m, unsigned short& l) {
    unsigned int u = __float_as_uint(v);
    h = (unsigned short)(u >> 16);
    float r1 = v - __uint_as_float(u & 0xFFFF0000u);
    unsigned int u1 = __float_as_uint(r1);
    m = (unsigned short)(u1 >> 16);
    float r2 = r1 - __uint_as_float(u1 & 0xFFFF0000u);
    l = (unsigned short)(__float_as_uint(r2) >> 16);
}

// ---------------- codebook norms ----------------
__global__ void esq_kernel(const float* __restrict__ cb, float* __restrict__ esq) {
    int c = blockIdx.x * 256 + threadIdx.x;
    float s = 0.f;
#pragma unroll
    for (int d4 = 0; d4 < NLAT; d4 += 4) {
        float4 v = *reinterpret_cast<const float4*>(&cb[(size_t)c * NLAT + d4]);
        s += v.x * v.x; s += v.y * v.y; s += v.z * v.z; s += v.w * v.w;
    }
    esq[c] = s;
}

// ---------------- prep: decoder weights ----------------
__global__ void prep_w1t(const float* __restrict__ dw1, unsigned short* __restrict__ w1t) {
    int idx = blockIdx.x * 256 + threadIdx.x;
    int l = idx >> 11, h = idx & 2047;
    w1t[h * 64 + l] = f2bf(dw1[l * 2048 + h]);
}
__global__ void prep_w2t(const float* __restrict__ dw2, unsigned short* __restrict__ w2t) {
    int idx = blockIdx.x * 256 + threadIdx.x;
    int k = idx >> 10, c = idx & 1023;
    w2t[(size_t)c * 2048 + k] = f2bf(dw2[(size_t)k * 1024 + c]);
}

// ---------------- prep: encoder w1 transpose + 3-way bf16 split ----------------
__global__ void prep_w1split(const float* __restrict__ w1,
                             unsigned short* __restrict__ w1hT,
                             unsigned short* __restrict__ w1mT,
                             unsigned short* __restrict__ w1lT) {
    __shared__ __align__(16) float tile[64][68];
    int kb = blockIdx.x & 15, hb = blockIdx.x >> 4;
    int k0 = kb * 64, h0 = hb * 64;
    int r = threadIdx.x >> 4, c4 = (threadIdx.x & 15) * 4;
#pragma unroll
    for (int i = 0; i < 4; i++) {
        int rr = r + 16 * i;
        float4 v = *reinterpret_cast<const float4*>(&w1[(size_t)(k0 + rr) * NHID + h0 + c4]);
        tile[rr][c4 + 0] = v.x; tile[rr][c4 + 1] = v.y;
        tile[rr][c4 + 2] = v.z; tile[rr][c4 + 3] = v.w;
    }
    __syncthreads();
#pragma unroll
    for (int i = 0; i < 4; i++) {
        int hh = r + 16 * i;
        unsigned short sh[4], sm[4], sl[4];
#pragma unroll
        for (int j = 0; j < 4; j++) {
            split3(tile[c4 + j][hh], sh[j], sm[j], sl[j]);
        }
        size_t addr = (size_t)(h0 + hh) * 1024 + k0 + c4;
        *reinterpret_cast<ushort4*>(&w1hT[addr]) = make_ushort4(sh[0], sh[1], sh[2], sh[3]);
        *reinterpret_cast<ushort4*>(&w1mT[addr]) = make_ushort4(sm[0], sm[1], sm[2], sm[3]);
        *reinterpret_cast<ushort4*>(&w1lT[addr]) = make_ushort4(sl[0], sl[1], sl[2], sl[3]);
    }
}

// ---------------- fused encoder (MFMA 3-split) + GEMM2 (fp32) + VQ top-2 ----------------
// R17 verbatim (proven end-to-end incl. graph replay).
__global__ __launch_bounds__(512)
void encvq_kernel(const float* __restrict__ x,
                  const unsigned short* __restrict__ w1hT,
                  const unsigned short* __restrict__ w1mT,
                  const unsigned short* __restrict__ w1lT,
                  const float* __restrict__ b1, const float* __restrict__ w2,
                  const float* __restrict__ b2, const float* __restrict__ cb,
                  const float* __restrict__ esq,
                  float* __restrict__ out, float* __restrict__ partials,
                  float* __restrict__ flags) {
    float* ze_out  = out + ZE_OFF;
    float* zq_out  = out + ZQ_OFF;
    float* idx_out = out + IDX_OFF;

    static __shared__ __align__(16) unsigned char smem[76800];
    unsigned short* xh  = (unsigned short*)(smem);
    unsigned short* xm  = (unsigned short*)(smem + 5120);
    unsigned short* xl  = (unsigned short*)(smem + 10240);
    unsigned short* bsh = (unsigned short*)(smem + 15360);
    unsigned short* bsm = (unsigned short*)(smem + 35840);
    unsigned short* bsl = (unsigned short*)(smem + 56320);
    float* hs  = (float*)(smem);
    float* w2s = (float*)(smem + 10240);
    float* zs  = (float*)(smem);
    float* cbs = (float*)(smem + 16384);
    __shared__ int   ridx2[64];
    __shared__ float zsq[64];
    __shared__ float lred[64];

    const int t = threadIdx.x;
    const int rg = t >> 5, cg = t & 31;
    const int wv = t >> 6, lane = t & 63;
    const int wr = wv >> 2, wc = wv & 3;
    const int lo = lane & 15, hi = lane >> 4;
    const int brow = blockIdx.x * 64;

    float2 zacc[4];
#pragma unroll
    for (int i = 0; i < 4; i++) zacc[i] = make_float2(0.f, 0.f);

    for (int jc = 0; jc < NHID; jc += 256) {
        // -------- GEMM1 (MFMA) --------
        v4f acc[2][4];
#pragma unroll
        for (int rt = 0; rt < 2; rt++)
#pragma unroll
            for (int ct = 0; ct < 4; ct++) acc[rt][ct] = (v4f){0.f, 0.f, 0.f, 0.f};

        for (int kc = 0; kc < NIN; kc += 32) {
            __syncthreads();
            {
                int row = t >> 3, seg = t & 7;
                float4 v = *reinterpret_cast<const float4*>(
                    &x[(size_t)(brow + row) * NIN + kc + seg * 4]);
                unsigned short sh[4], sm[4], sl[4];
                split3(v.x, sh[0], sm[0], sl[0]);
                split3(v.y, sh[1], sm[1], sl[1]);
                split3(v.z, sh[2], sm[2], sl[2]);
                split3(v.w, sh[3], sm[3], sl[3]);
                int a = row * 40 + seg * 4;
                *reinterpret_cast<ushort4*>(&xh[a]) = make_ushort4(sh[0], sh[1], sh[2], sh[3]);
                *reinterpret_cast<ushort4*>(&xm[a]) = make_ushort4(sm[0], sm[1], sm[2], sm[3]);
                *reinterpret_cast<ushort4*>(&xl[a]) = make_ushort4(sl[0], sl[1], sl[2], sl[3]);
            }
#pragma unroll
            for (int jj = 0; jj < 2; jj++) {
                int col = (t >> 2) + 128 * jj, segb = t & 3;
                size_t src = (size_t)(jc + col) * 1024 + kc + segb * 8;
                int dst = col * 40 + segb * 8;
                *reinterpret_cast<uint4*>(&bsh[dst]) = *reinterpret_cast<const uint4*>(&w1hT[src]);
                *reinterpret_cast<uint4*>(&bsm[dst]) = *reinterpret_cast<const uint4*>(&w1mT[src]);
                *reinterpret_cast<uint4*>(&bsl[dst]) = *reinterpret_cast<const uint4*>(&w1lT[src]);
            }
            __syncthreads();

            v8s Ah[2], Am[2], Al[2];
#pragma unroll
            for (int rt = 0; rt < 2; rt++) {
                int ra = (32 * wr + 16 * rt + lo) * 40 + hi * 8;
                Ah[rt] = *reinterpret_cast<const v8s*>(&xh[ra]);
                Am[rt] = *reinterpret_cast<const v8s*>(&xm[ra]);
                Al[rt] = *reinterpret_cast<const v8s*>(&xl[ra]);
            }
#pragma unroll
            for (int ct = 0; ct < 4; ct++) {
                int ba = (64 * wc + 16 * ct + lo) * 40 + hi * 8;
                v8s Bh = *reinterpret_cast<const v8s*>(&bsh[ba]);
                v8s Bm = *reinterpret_cast<const v8s*>(&bsm[ba]);
                v8s Bl = *reinterpret_cast<const v8s*>(&bsl[ba]);
#pragma unroll
                for (int rt = 0; rt < 2; rt++) {
                    acc[rt][ct] = __builtin_amdgcn_mfma_f32_16x16x32_bf16(Ah[rt], Bh, acc[rt][ct], 0, 0, 0);
                    acc[rt][ct] = __builtin_amdgcn_mfma_f32_16x16x32_bf16(Ah[rt], Bm, acc[rt][ct], 0, 0, 0);
                    acc[rt][ct] = __builtin_amdgcn_mfma_f32_16x16x32_bf16(Am[rt], Bh, acc[rt][ct], 0, 0, 0);
                    acc[rt][ct] = __builtin_amdgcn_mfma_f32_16x16x32_bf16(Ah[rt], Bl, acc[rt][ct], 0, 0, 0);
                    acc[rt][ct] = __builtin_amdgcn_mfma_f32_16x16x32_bf16(Al[rt], Bh, acc[rt][ct], 0, 0, 0);
                    acc[rt][ct] = __builtin_amdgcn_mfma_f32_16x16x32_bf16(Am[rt], Bm, acc[rt][ct], 0, 0, 0);
                }
            }
        }

        // -------- GEMM2 (fp32) --------
        for (int cs = 0; cs < 8; cs++) {
            __syncthreads();
            if (wc == (cs >> 1)) {
                int ctp = (cs & 1) * 2;
#pragma unroll
                for (int c2 = 0; c2 < 2; c2++) {
                    int ct2 = ctp + c2;
                    float bias = b1[jc + 64 * wc + 16 * ct2 + lo];
#pragma unroll
                    for (int rt = 0; rt < 2; rt++) {
#pragma unroll
                        for (int r = 0; r < 4; r++) {
                            int rl = 32 * wr + 16 * rt + 4 * hi + r;
                            hs[rl * 36 + 16 * c2 + lo] = fmaxf(acc[rt][ct2][r] + bias, 0.f);
                        }
                    }
                }
            }
            {
                int r = t >> 4, c4 = (t & 15) * 4;
                *reinterpret_cast<float4*>(&w2s[r * 68 + c4]) =
                    *reinterpret_cast<const float4*>(&w2[(size_t)(jc + 32 * cs + r) * NLAT + c4]);
            }
            __syncthreads();
#pragma unroll 4
            for (int k = 0; k < 32; k++) {
                float2 wvv = *reinterpret_cast<float2*>(&w2s[k * 68 + cg * 2]);
#pragma unroll
                for (int i = 0; i < 4; i++) {
                    float hv = hs[(rg + 16 * i) * 36 + k];
                    zacc[i].x += hv * wvv.x;
                    zacc[i].y += hv * wvv.y;
                }
            }
        }
    }

    __syncthreads();
    {
        float2 b2v = *reinterpret_cast<const float2*>(&b2[cg * 2]);
#pragma unroll
        for (int i = 0; i < 4; i++) {
            int row = brow + rg + 16 * i;
            float2 z = make_float2(zacc[i].x + b2v.x, zacc[i].y + b2v.y);
            *reinterpret_cast<float2*>(&zs[(rg + 16 * i) * 64 + cg * 2]) = z;
            *reinterpret_cast<float2*>(&ze_out[(size_t)row * NLAT + cg * 2]) = z;
        }
    }
    __syncthreads();

    // ---------------- VQ with top-2 tracking ----------------
    if (t < 64) {
        float s = 0.f;
#pragma unroll 16
        for (int d = 0; d < 64; d++) { float v = zs[t * 64 + d]; s += v * v; }
        zsq[t] = s;
    }
    __syncthreads();
    float zr[4];
#pragma unroll
    for (int i = 0; i < 4; i++) zr[i] = zsq[rg + 16 * i];

    float best[4], b2nd[4]; int bidx[4];
#pragma unroll
    for (int i = 0; i < 4; i++) { best[i] = FLTMAX; b2nd[i] = FLTMAX; bidx[i] = 0; }

    for (int cc = 0; cc < NEMB; cc += 128) {
        __syncthreads();
#pragma unroll
        for (int jj = 0; jj < 4; jj++) {
            int id = t + 512 * jj;
            int r = id >> 4, c4 = (id & 15) * 4;
            *reinterpret_cast<float4*>(&cbs[r * 68 + c4]) =
                *reinterpret_cast<const float4*>(&cb[(size_t)(cc + r) * NLAT + c4]);
        }
        __syncthreads();
        float dot[4][4];
#pragma unroll
        for (int i = 0; i < 4; i++)
#pragma unroll
            for (int j = 0; j < 4; j++) dot[i][j] = 0.f;
#pragma unroll 2
        for (int d4 = 0; d4 < 64; d4 += 4) {
            float4 zv[4];
#pragma unroll
            for (int i = 0; i < 4; i++)
                zv[i] = *reinterpret_cast<float4*>(&zs[(rg + 16 * i) * 64 + d4]);
#pragma unroll
            for (int j = 0; j < 4; j++) {
                float4 cv = *reinterpret_cast<float4*>(&cbs[(cg + 32 * j) * 68 + d4]);
#pragma unroll
                for (int i = 0; i < 4; i++) {
                    dot[i][j] += zv[i].x*cv.x + zv[i].y*cv.y + zv[i].z*cv.z + zv[i].w*cv.w;
                }
            }
        }
#pragma unroll
        for (int j = 0; j < 4; j++) {
            int cl = cg + 32 * j;
            float eq = esq[cc + cl];
#pragma unroll
            for (int i = 0; i < 4; i++) {
                float d2 = (zr[i] - 2.f * dot[i][j]) + eq;
                int c = cc + cl;
                if (d2 < best[i] || (d2 == best[i] && c < bidx[i])) {
                    b2nd[i] = fminf(best[i], b2nd[i]);
                    best[i] = d2; bidx[i] = c;
                } else {
                    b2nd[i] = fminf(b2nd[i], d2);
                }
            }
        }
    }
#pragma unroll
    for (int off = 16; off >= 1; off >>= 1) {
#pragma unroll
        for (int i = 0; i < 4; i++) {
            float ob  = __shfl_xor(best[i], off, 64);
            int   oi  = __shfl_xor(bidx[i], off, 64);
            float ob2 = __shfl_xor(b2nd[i], off, 64);
            if (ob < best[i] || (ob == best[i] && oi < bidx[i])) {
                b2nd[i] = fminf(best[i], ob2);
                best[i] = ob; bidx[i] = oi;
            } else {
                b2nd[i] = fminf(b2nd[i], ob);
            }
        }
    }
    if (cg == 0) {
#pragma unroll
        for (int i = 0; i < 4; i++) {
            ridx2[rg + 16 * i] = bidx[i];
            flags[brow + rg + 16 * i] = b2nd[i] - best[i];
        }
    }
    __syncthreads();
    if (t < 64) {
        int c = ridx2[t] & (NEMB - 1);
        int row = brow + t;
        idx_out[row] = (float)c;
        float s = 0.f;
#pragma unroll
        for (int d4 = 0; d4 < 64; d4 += 4) {
            float4 q = *reinterpret_cast<const float4*>(&cb[(size_t)c * NLAT + d4]);
            float z0 = zs[t * 64 + d4 + 0], z1 = zs[t * 64 + d4 + 1];
            float z2 = zs[t * 64 + d4 + 2], z3 = zs[t * 64 + d4 + 3];
            float dx = q.x - z0, dy = q.y - z1, dz = q.z - z2, dw = q.w - z3;
            s += dx*dx + dy*dy + dz*dz + dw*dw;
            *reinterpret_cast<float4*>(&zq_out[(size_t)row * NLAT + d4]) = q;
        }
        lred[t] = s;
    }
    __syncthreads();
    if (t == 0) {
        float s = 0.f;
        for (int q = 0; q < 64; q++) s += lred[q];
        partials[blockIdx.x] = s;
    }
}

// ---------------- fixup: fp32 re-decision for thin-gap rows (R17 verbatim) ----------------
__global__ __launch_bounds__(256)
void fixup_kernel(const float* __restrict__ x,  const float* __restrict__ w1,
                  const float* __restrict__ b1, const float* __restrict__ w2,
                  const float* __restrict__ b2, const float* __restrict__ cb,
                  const float* __restrict__ esq, const float* __restrict__ flags,
                  float* __restrict__ out) {
    float* zq_out  = out + ZQ_OFF;
    float* idx_out = out + IDX_OFF;
    __shared__ __align__(16) float xls[1024];
    __shared__ __align__(16) float hls[2048];
    __shared__ float zls[64];
    __shared__ float rb[256];
    __shared__ int   ri[256];
    __shared__ int   rowflags[16];
    const int t = threadIdx.x;
    const int brow = blockIdx.x * 16;

    if (t < 16) rowflags[t] = (flags[brow + t] < TAU) ? 1 : 0;
    __syncthreads();

    for (int rr = 0; rr < 16; rr++) {
        if (!rowflags[rr]) continue;                      // uniform branch
        int row = brow + rr;
        *reinterpret_cast<float4*>(&xls[t * 4]) =
            *reinterpret_cast<const float4*>(&x[(size_t)row * NIN + t * 4]);
        __syncthreads();
#pragma unroll
        for (int p = 0; p < 8; p++) {
            int j = t + 256 * p;
            float s0 = 0.f, s1 = 0.f, s2 = 0.f, s3 = 0.f;
            for (int k = 0; k < NIN; k += 4) {
                s0 += xls[k + 0] * w1[(size_t)(k + 0) * NHID + j];
                s1 += xls[k + 1] * w1[(size_t)(k + 1) * NHID + j];
                s2 += xls[k + 2] * w1[(size_t)(k + 2) * NHID + j];
                s3 += xls[k + 3] * w1[(size_t)(k + 3) * NHID + j];
            }
            hls[j] = fmaxf(((s0 + s1) + (s2 + s3)) + b1[j], 0.f);
        }
        __syncthreads();
        if (t < 64) {
            float s0 = 0.f, s1 = 0.f, s2 = 0.f, s3 = 0.f;
            for (int k = 0; k < NHID; k += 4) {
                s0 += hls[k + 0] * w2[(size_t)(k + 0) * NLAT + t];
                s1 += hls[k + 1] * w2[(size_t)(k + 1) * NLAT + t];
                s2 += hls[k + 2] * w2[(size_t)(k + 2) * NLAT + t];
                s3 += hls[k + 3] * w2[(size_t)(k + 3) * NLAT + t];
            }
            zls[t] = ((s0 + s1) + (s2 + s3)) + b2[t];
        }
        __syncthreads();
        float zsq_ = 0.f;
        for (int d = 0; d < NLAT; d++) zsq_ += zls[d] * zls[d];
        float bv = FLTMAX; int bi = 0;
        for (int p = 0; p < 16; p++) {
            int c = t + 256 * p;                          // ascending per thread
            float s0 = 0.f, s1 = 0.f, s2 = 0.f, s3 = 0.f;
            const float* cr = &cb[(size_t)c * NLAT];
            for (int d = 0; d < NLAT; d += 4) {
                s0 += zls[d + 0] * cr[d + 0];
                s1 += zls[d + 1] * cr[d + 1];
                s2 += zls[d + 2] * cr[d + 2];
                s3 += zls[d + 3] * cr[d + 3];
            }
            float d2 = (zsq_ - 2.f * ((s0 + s1) + (s2 + s3))) + esq[c];
            if (d2 < bv || (d2 == bv && c < bi)) { bv = d2; bi = c; }
        }
        rb[t] = bv; ri[t] = bi;
        __syncthreads();
        for (int s2r = 128; s2r >= 1; s2r >>= 1) {
            if (t < s2r) {
                float ob = rb[t + s2r]; int oi = ri[t + s2r];
                if (ob < rb[t] || (ob == rb[t] && oi < ri[t])) { rb[t] = ob; ri[t] = oi; }
            }
            __syncthreads();
        }
        if (t < 16) {
            int c = ri[0];
            if (t == 0) idx_out[row] = (float)c;
            float4 q = *reinterpret_cast<const float4*>(&cb[(size_t)c * NLAT + t * 4]);
            *reinterpret_cast<float4*>(&zq_out[(size_t)row * NLAT + t * 4]) = q;
        }
        __syncthreads();
    }
}

// ---------------- loss ----------------
__global__ void loss_kernel(const float* __restrict__ partials, float* __restrict__ out_loss) {
    if (threadIdx.x == 0 && blockIdx.x == 0) {
        float s = 0.f;
        for (int i = 0; i < 512; i++) s += partials[i];
        *out_loss = (1.f + BETA) * s / (float)((size_t)NB * NLAT);
    }
}

// ---------------- MFMA decoder (verified, unchanged) ----------------
__global__ __launch_bounds__(256)
void dec_kernel(const float* __restrict__ out_base,
                const unsigned short* __restrict__ w1t,
                const unsigned short* __restrict__ w2t,
                const float* __restrict__ b1, const float* __restrict__ b2,
                float* __restrict__ xr) {
    const float* zq_in = out_base + ZQ_OFF;

    __shared__ __align__(16) unsigned short zqb[64 * 72];
    __shared__ __align__(16) unsigned short w1b[64 * 72];
    __shared__ __align__(16) unsigned short hdb[64 * 72];
    __shared__ __align__(16) unsigned short w2b[256 * 72];

    const int t = threadIdx.x;
    const int w = t >> 6, lane = t & 63, lo = lane & 15, hi = lane >> 4;
    const int rb = blockIdx.x >> 2, cbk = blockIdx.x & 3;
    const int brow = rb * 64, cbase = cbk * 256;

    {
        int row = t & 63, m = t >> 6;
        const float* src = &zq_in[(size_t)(brow + row) * NLAT + m * 16];
        unsigned int us[8];
#pragma unroll
        for (int j = 0; j < 4; j++) {
            float4 v = *reinterpret_cast<const float4*>(src + 4 * j);
            us[2*j]   = (unsigned int)f2bf(v.x) | ((unsigned int)f2bf(v.y) << 16);
            us[2*j+1] = (unsigned int)f2bf(v.z) | ((unsigned int)f2bf(v.w) << 16);
        }
        uint4 p0 = make_uint4(us[0], us[1], us[2], us[3]);
        uint4 p1 = make_uint4(us[4], us[5], us[6], us[7]);
        *reinterpret_cast<uint4*>(&zqb[row * 72 + m * 16 + 0]) = p0;
        *reinterpret_cast<uint4*>(&zqb[row * 72 + m * 16 + 8]) = p1;
    }

    v4f facc[4][4];
#pragma unroll
    for (int i = 0; i < 4; i++)
#pragma unroll
        for (int j = 0; j < 4; j++) facc[i][j] = (v4f){0.f, 0.f, 0.f, 0.f};

    for (int hc = 0; hc < NHID; hc += 64) {
        __syncthreads();
        {
            int cl = t & 63, mm = (t >> 6) * 2;
#pragma unroll
            for (int j = 0; j < 2; j++) {
                uint4 v = *reinterpret_cast<const uint4*>(&w1t[(size_t)(hc + cl) * 64 + (mm + j) * 8]);
                *reinterpret_cast<uint4*>(&w1b[cl * 72 + (mm + j) * 8]) = v;
            }
        }
        {
            const unsigned short* src = &w2t[(size_t)(cbase + t) * 2048 + hc];
#pragma unroll
            for (int j = 0; j < 8; j++) {
                uint4 v = *reinterpret_cast<const uint4*>(src + j * 8);
                *reinterpret_cast<uint4*>(&w2b[t * 72 + j * 8]) = v;
            }
        }
        __syncthreads();

        v8s a0 = *reinterpret_cast<const v8s*>(&zqb[(16 * w + lo) * 72 +  0 + hi * 8]);
        v8s a1 = *reinterpret_cast<const v8s*>(&zqb[(16 * w + lo) * 72 + 32 + hi * 8]);
#pragma unroll
        for (int ct = 0; ct < 4; ct++) {
            v8s bb0 = *reinterpret_cast<const v8s*>(&w1b[(16 * ct + lo) * 72 +  0 + hi * 8]);
            v8s bb1 = *reinterpret_cast<const v8s*>(&w1b[(16 * ct + lo) * 72 + 32 + hi * 8]);
            v4f acc = (v4f){0.f, 0.f, 0.f, 0.f};
            acc = __builtin_amdgcn_mfma_f32_16x16x32_bf16(a0, bb0, acc, 0, 0, 0);
            acc = __builtin_amdgcn_mfma_f32_16x16x32_bf16(a1, bb1, acc, 0, 0, 0);
            float bias = b1[hc + 16 * ct + lo];
#pragma unroll
            for (int r = 0; r < 4; r++) {
                float hv = fmaxf(acc[r] + bias, 0.f);
                hdb[(16 * w + 4 * hi + r) * 72 + 16 * ct + lo] = f2bf(hv);
            }
        }
        __syncthreads();

#pragma unroll
        for (int kk = 0; kk < 2; kk++) {
            v8s af[4];
#pragma unroll
            for (int rt = 0; rt < 4; rt++)
                af[rt] = *reinterpret_cast<const v8s*>(&hdb[(16 * rt + lo) * 72 + kk * 32 + hi * 8]);
#pragma unroll
            for (int ctl = 0; ctl < 4; ctl++) {
                v8s bf_ = *reinterpret_cast<const v8s*>(&w2b[(64 * w + 16 * ctl + lo) * 72 + kk * 32 + hi * 8]);
#pragma unroll
                for (int rt = 0; rt < 4; rt++)
                    facc[rt][ctl] = __builtin_amdgcn_mfma_f32_16x16x32_bf16(af[rt], bf_, facc[rt][ctl], 0, 0, 0);
            }
        }
    }

#pragma unroll
    for (int ctl = 0; ctl < 4; ctl++) {
        int col = cbase + 64 * w + 16 * ctl + lo;
        float bias = b2[col];
#pragma unroll
        for (int rt = 0; rt < 4; rt++) {
#pragma unroll
            for (int r = 0; r < 4; r++) {
                int row = brow + 16 * rt + 4 * hi + r;
                xr[(size_t)row * NIN + col] = facc[rt][ctl][r] + bias;
            }
        }
    }
}

extern "C" void kernel_launch(void* const* d_in, const int* in_sizes, int n_in,
                              void* d_out, int out_size, void* d_ws, size_t ws_size,
                              hipStream_t stream) {
    (void)in_sizes; (void)n_in; (void)out_size; (void)ws_size;
    const float* x   = (const float*)d_in[0];
    const float* ew1 = (const float*)d_in[1];
    const float* eb1 = (const float*)d_in[2];
    const float* ew2 = (const float*)d_in[3];
    const float* eb2 = (const float*)d_in[4];
    const float* cb  = (const float*)d_in[5];
    const float* dw1 = (const float*)d_in[6];
    const float* db1 = (const float*)d_in[7];
    const float* dw2 = (const float*)d_in[8];
    const float* db2 = (const float*)d_in[9];

    float* out  = (float*)d_out;
    float* part = (float*)d_ws + PART_WS_F;
    float* esq  = (float*)((char*)d_ws + ESQ_WS_B);
    unsigned short* w1t  = (unsigned short*)((char*)d_ws + W1T_WS_B);
    unsigned short* w2t  = (unsigned short*)((char*)d_ws + W2T_WS_B);
    unsigned short* w1hT = (unsigned short*)((char*)d_ws + W1HT_WS_B);
    unsigned short* w1mT = (unsigned short*)((char*)d_ws + W1MT_WS_B);
    unsigned short* w1lT = (unsigned short*)((char*)d_ws + W1LT_WS_B);
    float* flags = (float*)((char*)d_ws + FLAGS_WS_B);

    esq_kernel<<<NEMB / 256, 256, 0, stream>>>(cb, esq);
    prep_w1t<<<512, 256, 0, stream>>>(dw1, w1t);
    prep_w2t<<<8192, 256, 0, stream>>>(dw2, w2t);
    prep_w1split<<<512, 256, 0, stream>>>(ew1, w1hT, w1mT, w1lT);
    encvq_kernel<<<NB / 64, 512, 0, stream>>>(x, w1hT, w1mT, w1lT, eb1, ew2, eb2,
                                              cb, esq, out, part, flags);
    fixup_kernel<<<NB / 16, 256, 0, stream>>>(x, ew1, eb1, ew2, eb2, cb, esq, flags, out);
    loss_kernel<<<1, 64, 0, stream>>>(part, out + LOSS_OFF);
    dec_kernel<<<(NB / 64) * 4, 256, 0, stream>>>(out, w1t, w2t, db1, db2, out + XR_OFF);
}

// Round 24
// 2085.378 us; speedup vs baseline: 1.1016x; 1.0069x over previous
//
#include <hip/hip_runtime.h>
#include <hip/hip_bf16.h>

#define NB    32768
#define NIN   1024
#define NHID  2048
#define NLAT  64
#define NEMB  4096
#define BETA  0.25f
#define TAU   0.004f

#define FLTMAX 3.402823466e+38f

// ---- output layout (FLOAT32 elements) ----
#define XR_OFF   0
#define ZE_OFF   33554432
#define ZQ_OFF   35651584
#define IDX_OFF  37748736
#define LOSS_OFF 37781504

// ---- ws layout (bytes) — R17 proven map (max 17,190,912) ----
#define PART_WS_F   0          // 512 f32 loss partials
#define ESQ_WS_B    4096       // 4096 f32
#define W1T_WS_B    20480      // dec w1t bf16 [2048][64]
#define W2T_WS_B    282624     // dec w2t bf16 [1024][2048] -> ends 4476928
#define W1HT_WS_B   4476928    // enc w1 split hi  bf16 [2048 h][1024 k]
#define W1MT_WS_B   8671232    // enc w1 split mid
#define W1LT_WS_B   12865536   // enc w1 split lo  -> ends 17059840
#define FLAGS_WS_B  17059840   // 32768 f32 gaps -> ends 17190912

typedef short v8s __attribute__((ext_vector_type(8)));
typedef float v4f __attribute__((ext_vector_type(4)));

static __device__ __forceinline__ unsigned short f2bf(float f) {
    union { __hip_bfloat16 h; unsigned short u; } v;
    v.h = __float2bfloat16(f);
    return v.u;
}

// exact truncation split: v == bh + bm + bl (as bf16-representable f32s)
static __device__ __forceinline__ void split3(float v, unsigned short& h,
                                              unsigned short& m, unsigned short& l) {
    unsigned int u = __float_as_uint(v);
    h = (unsigned short)(u >> 16);
    float r1 = v - __uint_as_float(u & 0xFFFF0000u);
    unsigned int u1 = __float_as_uint(r1);
    m = (unsigned short)(u1 >> 16);
    float r2 = r1 - __uint_as_float(u1 & 0xFFFF0000u);
    l = (unsigned short)(__float_as_uint(r2) >> 16);
}

// ---------------- codebook norms ----------------
__global__ void esq_kernel(const float* __restrict__ cb, float* __restrict__ esq) {
    int c = blockIdx.x * 256 + threadIdx.x;
    float s = 0.f;
#pragma unroll
    for (int d4 = 0; d4 < NLAT; d4 += 4) {
        float4 v = *reinterpret_cast<const float4*>(&cb[(size_t)c * NLAT + d4]);
        s += v.x * v.x; s += v.y * v.y; s += v.z * v.z; s += v.w * v.w;
    }
    esq[c] = s;
}

// ---------------- prep: decoder weights ----------------
__global__ void prep_w1t(const float* __restrict__ dw1, unsigned short* __restrict__ w1t) {
    int idx = blockIdx.x * 256 + threadIdx.x;
    int l = idx >> 11, h = idx & 2047;
    w1t[h * 64 + l] = f2bf(dw1[l * 2048 + h]);
}
__global__ void prep_w2t(const float* __restrict__ dw2, unsigned short* __restrict__ w2t) {
    int idx = blockIdx.x * 256 + threadIdx.x;
    int k = idx >> 10, c = idx & 1023;
    w2t[(size_t)c * 2048 + k] = f2bf(dw2[(size_t)k * 1024 + c]);
}

// ---------------- prep: encoder w1 transpose + 3-way bf16 split ----------------
__global__ void prep_w1split(const float* __restrict__ w1,
                             unsigned short* __restrict__ w1hT,
                             unsigned short* __restrict__ w1mT,
                             unsigned short* __restrict__ w1lT) {
    __shared__ __align__(16) float tile[64][68];
    int kb = blockIdx.x & 15, hb = blockIdx.x >> 4;
    int k0 = kb * 64, h0 = hb * 64;
    int r = threadIdx.x >> 4, c4 = (threadIdx.x & 15) * 4;
#pragma unroll
    for (int i = 0; i < 4; i++) {
        int rr = r + 16 * i;
        float4 v = *reinterpret_cast<const float4*>(&w1[(size_t)(k0 + rr) * NHID + h0 + c4]);
        tile[rr][c4 + 0] = v.x; tile[rr][c4 + 1] = v.y;
        tile[rr][c4 + 2] = v.z; tile[rr][c4 + 3] = v.w;
    }
    __syncthreads();
#pragma unroll
    for (int i = 0; i < 4; i++) {
        int hh = r + 16 * i;
        unsigned short sh[4], sm[4], sl[4];
#pragma unroll
        for (int j = 0; j < 4; j++) {
            split3(tile[c4 + j][hh], sh[j], sm[j], sl[j]);
        }
        size_t addr = (size_t)(h0 + hh) * 1024 + k0 + c4;
        *reinterpret_cast<ushort4*>(&w1hT[addr]) = make_ushort4(sh[0], sh[1], sh[2], sh[3]);
        *reinterpret_cast<ushort4*>(&w1mT[addr]) = make_ushort4(sm[0], sm[1], sm[2], sm[3]);
        *reinterpret_cast<ushort4*>(&w1lT[addr]) = make_ushort4(sl[0], sl[1], sl[2], sl[3]);
    }
}

// ---------------- fused encoder (MFMA 3-split) + GEMM2 (fp32) + VQ top-2 ----------------
// R17/R22 verbatim (proven end-to-end incl. graph replay, twice).
__global__ __launch_bounds__(512)
void encvq_kernel(const float* __restrict__ x,
                  const unsigned short* __restrict__ w1hT,
                  const unsigned short* __restrict__ w1mT,
                  const unsigned short* __restrict__ w1lT,
                  const float* __restrict__ b1, const float* __restrict__ w2,
                  const float* __restrict__ b2, const float* __restrict__ cb,
                  const float* __restrict__ esq,
                  float* __restrict__ out, float* __restrict__ partials,
                  float* __restrict__ flags) {
    float* ze_out  = out + ZE_OFF;
    float* zq_out  = out + ZQ_OFF;
    float* idx_out = out + IDX_OFF;

    static __shared__ __align__(16) unsigned char smem[76800];
    unsigned short* xh  = (unsigned short*)(smem);
    unsigned short* xm  = (unsigned short*)(smem + 5120);
    unsigned short* xl  = (unsigned short*)(smem + 10240);
    unsigned short* bsh = (unsigned short*)(smem + 15360);
    unsigned short* bsm = (unsigned short*)(smem + 35840);
    unsigned short* bsl = (unsigned short*)(smem + 56320);
    float* hs  = (float*)(smem);
    float* w2s = (float*)(smem + 10240);
    float* zs  = (float*)(smem);
    float* cbs = (float*)(smem + 16384);
    __shared__ int   ridx2[64];
    __shared__ float zsq[64];
    __shared__ float lred[64];

    const int t = threadIdx.x;
    const int rg = t >> 5, cg = t & 31;
    const int wv = t >> 6, lane = t & 63;
    const int wr = wv >> 2, wc = wv & 3;
    const int lo = lane & 15, hi = lane >> 4;
    const int brow = blockIdx.x * 64;

    float2 zacc[4];
#pragma unroll
    for (int i = 0; i < 4; i++) zacc[i] = make_float2(0.f, 0.f);

    for (int jc = 0; jc < NHID; jc += 256) {
        // -------- GEMM1 (MFMA) --------
        v4f acc[2][4];
#pragma unroll
        for (int rt = 0; rt < 2; rt++)
#pragma unroll
            for (int ct = 0; ct < 4; ct++) acc[rt][ct] = (v4f){0.f, 0.f, 0.f, 0.f};

        for (int kc = 0; kc < NIN; kc += 32) {
            __syncthreads();
            {
                int row = t >> 3, seg = t & 7;
                float4 v = *reinterpret_cast<const float4*>(
                    &x[(size_t)(brow + row) * NIN + kc + seg * 4]);
                unsigned short sh[4], sm[4], sl[4];
                split3(v.x, sh[0], sm[0], sl[0]);
                split3(v.y, sh[1], sm[1], sl[1]);
                split3(v.z, sh[2], sm[2], sl[2]);
                split3(v.w, sh[3], sm[3], sl[3]);
                int a = row * 40 + seg * 4;
                *reinterpret_cast<ushort4*>(&xh[a]) = make_ushort4(sh[0], sh[1], sh[2], sh[3]);
                *reinterpret_cast<ushort4*>(&xm[a]) = make_ushort4(sm[0], sm[1], sm[2], sm[3]);
                *reinterpret_cast<ushort4*>(&xl[a]) = make_ushort4(sl[0], sl[1], sl[2], sl[3]);
            }
#pragma unroll
            for (int jj = 0; jj < 2; jj++) {
                int col = (t >> 2) + 128 * jj, segb = t & 3;
                size_t src = (size_t)(jc + col) * 1024 + kc + segb * 8;
                int dst = col * 40 + segb * 8;
                *reinterpret_cast<uint4*>(&bsh[dst]) = *reinterpret_cast<const uint4*>(&w1hT[src]);
                *reinterpret_cast<uint4*>(&bsm[dst]) = *reinterpret_cast<const uint4*>(&w1mT[src]);
                *reinterpret_cast<uint4*>(&bsl[dst]) = *reinterpret_cast<const uint4*>(&w1lT[src]);
            }
            __syncthreads();

            v8s Ah[2], Am[2], Al[2];
#pragma unroll
            for (int rt = 0; rt < 2; rt++) {
                int ra = (32 * wr + 16 * rt + lo) * 40 + hi * 8;
                Ah[rt] = *reinterpret_cast<const v8s*>(&xh[ra]);
                Am[rt] = *reinterpret_cast<const v8s*>(&xm[ra]);
                Al[rt] = *reinterpret_cast<const v8s*>(&xl[ra]);
            }
#pragma unroll
            for (int ct = 0; ct < 4; ct++) {
                int ba = (64 * wc + 16 * ct + lo) * 40 + hi * 8;
                v8s Bh = *reinterpret_cast<const v8s*>(&bsh[ba]);
                v8s Bm = *reinterpret_cast<const v8s*>(&bsm[ba]);
                v8s Bl = *reinterpret_cast<const v8s*>(&bsl[ba]);
#pragma unroll
                for (int rt = 0; rt < 2; rt++) {
                    acc[rt][ct] = __builtin_amdgcn_mfma_f32_16x16x32_bf16(Ah[rt], Bh, acc[rt][ct], 0, 0, 0);
                    acc[rt][ct] = __builtin_amdgcn_mfma_f32_16x16x32_bf16(Ah[rt], Bm, acc[rt][ct], 0, 0, 0);
                    acc[rt][ct] = __builtin_amdgcn_mfma_f32_16x16x32_bf16(Am[rt], Bh, acc[rt][ct], 0, 0, 0);
                    acc[rt][ct] = __builtin_amdgcn_mfma_f32_16x16x32_bf16(Ah[rt], Bl, acc[rt][ct], 0, 0, 0);
                    acc[rt][ct] = __builtin_amdgcn_mfma_f32_16x16x32_bf16(Al[rt], Bh, acc[rt][ct], 0, 0, 0);
                    acc[rt][ct] = __builtin_amdgcn_mfma_f32_16x16x32_bf16(Am[rt], Bm, acc[rt][ct], 0, 0, 0);
                }
            }
        }

        // -------- GEMM2 (fp32) --------
        for (int cs = 0; cs < 8; cs++) {
            __syncthreads();
            if (wc == (cs >> 1)) {
                int ctp = (cs & 1) * 2;
#pragma unroll
                for (int c2 = 0; c2 < 2; c2++) {
                    int ct2 = ctp + c2;
                    float bias = b1[jc + 64 * wc + 16 * ct2 + lo];
#pragma unroll
                    for (int rt = 0; rt < 2; rt++) {
#pragma unroll
                        for (int r = 0; r < 4; r++) {
                            int rl = 32 * wr + 16 * rt + 4 * hi + r;
                            hs[rl * 36 + 16 * c2 + lo] = fmaxf(acc[rt][ct2][r] + bias, 0.f);
                        }
                    }
                }
            }
            {
                int r = t >> 4, c4 = (t & 15) * 4;
                *reinterpret_cast<float4*>(&w2s[r * 68 + c4]) =
                    *reinterpret_cast<const float4*>(&w2[(size_t)(jc + 32 * cs + r) * NLAT + c4]);
            }
            __syncthreads();
#pragma unroll 4
            for (int k = 0; k < 32; k++) {
                float2 wvv = *reinterpret_cast<float2*>(&w2s[k * 68 + cg * 2]);
#pragma unroll
                for (int i = 0; i < 4; i++) {
                    float hv = hs[(rg + 16 * i) * 36 + k];
                    zacc[i].x += hv * wvv.x;
                    zacc[i].y += hv * wvv.y;
                }
            }
        }
    }

    __syncthreads();
    {
        float2 b2v = *reinterpret_cast<const float2*>(&b2[cg * 2]);
#pragma unroll
        for (int i = 0; i < 4; i++) {
            int row = brow + rg + 16 * i;
            float2 z = make_float2(zacc[i].x + b2v.x, zacc[i].y + b2v.y);
            *reinterpret_cast<float2*>(&zs[(rg + 16 * i) * 64 + cg * 2]) = z;
            *reinterpret_cast<float2*>(&ze_out[(size_t)row * NLAT + cg * 2]) = z;
        }
    }
    __syncthreads();

    // ---------------- VQ with top-2 tracking ----------------
    if (t < 64) {
        float s = 0.f;
#pragma unroll 16
        for (int d = 0; d < 64; d++) { float v = zs[t * 64 + d]; s += v * v; }
        zsq[t] = s;
    }
    __syncthreads();
    float zr[4];
#pragma unroll
    for (int i = 0; i < 4; i++) zr[i] = zsq[rg + 16 * i];

    float best[4], b2nd[4]; int bidx[4];
#pragma unroll
    for (int i = 0; i < 4; i++) { best[i] = FLTMAX; b2nd[i] = FLTMAX; bidx[i] = 0; }

    for (int cc = 0; cc < NEMB; cc += 128) {
        __syncthreads();
#pragma unroll
        for (int jj = 0; jj < 4; jj++) {
            int id = t + 512 * jj;
            int r = id >> 4, c4 = (id & 15) * 4;
            *reinterpret_cast<float4*>(&cbs[r * 68 + c4]) =
                *reinterpret_cast<const float4*>(&cb[(size_t)(cc + r) * NLAT + c4]);
        }
        __syncthreads();
        float dot[4][4];
#pragma unroll
        for (int i = 0; i < 4; i++)
#pragma unroll
            for (int j = 0; j < 4; j++) dot[i][j] = 0.f;
#pragma unroll 2
        for (int d4 = 0; d4 < 64; d4 += 4) {
            float4 zv[4];
#pragma unroll
            for (int i = 0; i < 4; i++)
                zv[i] = *reinterpret_cast<float4*>(&zs[(rg + 16 * i) * 64 + d4]);
#pragma unroll
            for (int j = 0; j < 4; j++) {
                float4 cv = *reinterpret_cast<float4*>(&cbs[(cg + 32 * j) * 68 + d4]);
#pragma unroll
                for (int i = 0; i < 4; i++) {
                    dot[i][j] += zv[i].x*cv.x + zv[i].y*cv.y + zv[i].z*cv.z + zv[i].w*cv.w;
                }
            }
        }
#pragma unroll
        for (int j = 0; j < 4; j++) {
            int cl = cg + 32 * j;
            float eq = esq[cc + cl];
#pragma unroll
            for (int i = 0; i < 4; i++) {
                float d2 = (zr[i] - 2.f * dot[i][j]) + eq;
                int c = cc + cl;
                if (d2 < best[i] || (d2 == best[i] && c < bidx[i])) {
                    b2nd[i] = fminf(best[i], b2nd[i]);
                    best[i] = d2; bidx[i] = c;
                } else {
                    b2nd[i] = fminf(b2nd[i], d2);
                }
            }
        }
    }
#pragma unroll
    for (int off = 16; off >= 1; off >>= 1) {
#pragma unroll
        for (int i = 0; i < 4; i++) {
            float ob  = __shfl_xor(best[i], off, 64);
            int   oi  = __shfl_xor(bidx[i], off, 64);
            float ob2 = __shfl_xor(b2nd[i], off, 64);
            if (ob < best[i] || (ob == best[i] && oi < bidx[i])) {
                b2nd[i] = fminf(best[i], ob2);
                best[i] = ob; bidx[i] = oi;
            } else {
                b2nd[i] = fminf(b2nd[i], ob);
            }
        }
    }
    if (cg == 0) {
#pragma unroll
        for (int i = 0; i < 4; i++) {
            ridx2[rg + 16 * i] = bidx[i];
            flags[brow + rg + 16 * i] = b2nd[i] - best[i];
        }
    }
    __syncthreads();
    if (t < 64) {
        int c = ridx2[t] & (NEMB - 1);
        int row = brow + t;
        idx_out[row] = (float)c;
        float s = 0.f;
#pragma unroll
        for (int d4 = 0; d4 < 64; d4 += 4) {
            float4 q = *reinterpret_cast<const float4*>(&cb[(size_t)c * NLAT + d4]);
            float z0 = zs[t * 64 + d4 + 0], z1 = zs[t * 64 + d4 + 1];
            float z2 = zs[t * 64 + d4 + 2], z3 = zs[t * 64 + d4 + 3];
            float dx = q.x - z0, dy = q.y - z1, dz = q.z - z2, dw = q.w - z3;
            s += dx*dx + dy*dy + dz*dz + dw*dw;
            *reinterpret_cast<float4*>(&zq_out[(size_t)row * NLAT + d4]) = q;
        }
        lred[t] = s;
    }
    __syncthreads();
    if (t == 0) {
        float s = 0.f;
        for (int q = 0; q < 64; q++) s += lred[q];
        partials[blockIdx.x] = s;
    }
}

// ---------------- fixup: fp32 re-decision for thin-gap rows (R17 verbatim) ----------------
__global__ __launch_bounds__(256)
void fixup_kernel(const float* __restrict__ x,  const float* __restrict__ w1,
                  const float* __restrict__ b1, const float* __restrict__ w2,
                  const float* __restrict__ b2, const float* __restrict__ cb,
                  const float* __restrict__ esq, const float* __restrict__ flags,
                  float* __restrict__ out) {
    float* zq_out  = out + ZQ_OFF;
    float* idx_out = out + IDX_OFF;
    __shared__ __align__(16) float xls[1024];
    __shared__ __align__(16) float hls[2048];
    __shared__ float zls[64];
    __shared__ float rb[256];
    __shared__ int   ri[256];
    __shared__ int   rowflags[16];
    const int t = threadIdx.x;
    const int brow = blockIdx.x * 16;

    if (t < 16) rowflags[t] = (flags[brow + t] < TAU) ? 1 : 0;
    __syncthreads();

    for (int rr = 0; rr < 16; rr++) {
        if (!rowflags[rr]) continue;                      // uniform branch
        int row = brow + rr;
        *reinterpret_cast<float4*>(&xls[t * 4]) =
            *reinterpret_cast<const float4*>(&x[(size_t)row * NIN + t * 4]);
        __syncthreads();
#pragma unroll
        for (int p = 0; p < 8; p++) {
            int j = t + 256 * p;
            float s0 = 0.f, s1 = 0.f, s2 = 0.f, s3 = 0.f;
            for (int k = 0; k < NIN; k += 4) {
                s0 += xls[k + 0] * w1[(size_t)(k + 0) * NHID + j];
                s1 += xls[k + 1] * w1[(size_t)(k + 1) * NHID + j];
                s2 += xls[k + 2] * w1[(size_t)(k + 2) * NHID + j];
                s3 += xls[k + 3] * w1[(size_t)(k + 3) * NHID + j];
            }
            hls[j] = fmaxf(((s0 + s1) + (s2 + s3)) + b1[j], 0.f);
        }
        __syncthreads();
        if (t < 64) {
            float s0 = 0.f, s1 = 0.f, s2 = 0.f, s3 = 0.f;
            for (int k = 0; k < NHID; k += 4) {
                s0 += hls[k + 0] * w2[(size_t)(k + 0) * NLAT + t];
                s1 += hls[k + 1] * w2[(size_t)(k + 1) * NLAT + t];
                s2 += hls[k + 2] * w2[(size_t)(k + 2) * NLAT + t];
                s3 += hls[k + 3] * w2[(size_t)(k + 3) * NLAT + t];
            }
            zls[t] = ((s0 + s1) + (s2 + s3)) + b2[t];
        }
        __syncthreads();
        float zsq_ = 0.f;
        for (int d = 0; d < NLAT; d++) zsq_ += zls[d] * zls[d];
        float bv = FLTMAX; int bi = 0;
        for (int p = 0; p < 16; p++) {
            int c = t + 256 * p;                          // ascending per thread
            float s0 = 0.f, s1 = 0.f, s2 = 0.f, s3 = 0.f;
            const float* cr = &cb[(size_t)c * NLAT];
            for (int d = 0; d < NLAT; d += 4) {
                s0 += zls[d + 0] * cr[d + 0];
                s1 += zls[d + 1] * cr[d + 1];
                s2 += zls[d + 2] * cr[d + 2];
                s3 += zls[d + 3] * cr[d + 3];
            }
            float d2 = (zsq_ - 2.f * ((s0 + s1) + (s2 + s3))) + esq[c];
            if (d2 < bv || (d2 == bv && c < bi)) { bv = d2; bi = c; }
        }
        rb[t] = bv; ri[t] = bi;
        __syncthreads();
        for (int s2r = 128; s2r >= 1; s2r >>= 1) {
            if (t < s2r) {
                float ob = rb[t + s2r]; int oi = ri[t + s2r];
                if (ob < rb[t] || (ob == rb[t] && oi < ri[t])) { rb[t] = ob; ri[t] = oi; }
            }
            __syncthreads();
        }
        if (t < 16) {
            int c = ri[0];
            if (t == 0) idx_out[row] = (float)c;
            float4 q = *reinterpret_cast<const float4*>(&cb[(size_t)c * NLAT + t * 4]);
            *reinterpret_cast<float4*>(&zq_out[(size_t)row * NLAT + t * 4]) = q;
        }
        __syncthreads();
    }
}

// ---------------- loss ----------------
__global__ void loss_kernel(const float* __restrict__ partials, float* __restrict__ out_loss) {
    if (threadIdx.x == 0 && blockIdx.x == 0) {
        float s = 0.f;
        for (int i = 0; i < 512; i++) s += partials[i];
        *out_loss = (1.f + BETA) * s / (float)((size_t)NB * NLAT);
    }
}

// ---------------- MFMA decoder (verified, unchanged) ----------------
__global__ __launch_bounds__(256)
void dec_kernel(const float* __restrict__ out_base,
                const unsigned short* __restrict__ w1t,
                const unsigned short* __restrict__ w2t,
                const float* __restrict__ b1, const float* __restrict__ b2,
                float* __restrict__ xr) {
    const float* zq_in = out_base + ZQ_OFF;

    __shared__ __align__(16) unsigned short zqb[64 * 72];
    __shared__ __align__(16) unsigned short w1b[64 * 72];
    __shared__ __align__(16) unsigned short hdb[64 * 72];
    __shared__ __align__(16) unsigned short w2b[256 * 72];

    const int t = threadIdx.x;
    const int w = t >> 6, lane = t & 63, lo = lane & 15, hi = lane >> 4;
    const int rb = blockIdx.x >> 2, cbk = blockIdx.x & 3;
    const int brow = rb * 64, cbase = cbk * 256;

    {
        int row = t & 63, m = t >> 6;
        const float* src = &zq_in[(size_t)(brow + row) * NLAT + m * 16];
        unsigned int us[8];
#pragma unroll
        for (int j = 0; j < 4; j++) {
            float4 v = *reinterpret_cast<const float4*>(src + 4 * j);
            us[2*j]   = (unsigned int)f2bf(v.x) | ((unsigned int)f2bf(v.y) << 16);
            us[2*j+1] = (unsigned int)f2bf(v.z) | ((unsigned int)f2bf(v.w) << 16);
        }
        uint4 p0 = make_uint4(us[0], us[1], us[2], us[3]);
        uint4 p1 = make_uint4(us[4], us[5], us[6], us[7]);
        *reinterpret_cast<uint4*>(&zqb[row * 72 + m * 16 + 0]) = p0;
        *reinterpret_cast<uint4*>(&zqb[row * 72 + m * 16 + 8]) = p1;
    }

    v4f facc[4][4];
#pragma unroll
    for (int i = 0; i < 4; i++)
#pragma unroll
        for (int j = 0; j < 4; j++) facc[i][j] = (v4f){0.f, 0.f, 0.f, 0.f};

    for (int hc = 0; hc < NHID; hc += 64) {
        __syncthreads();
        {
            int cl = t & 63, mm = (t >> 6) * 2;
#pragma unroll
            for (int j = 0; j < 2; j++) {
                uint4 v = *reinterpret_cast<const uint4*>(&w1t[(size_t)(hc + cl) * 64 + (mm + j) * 8]);
                *reinterpret_cast<uint4*>(&w1b[cl * 72 + (mm + j) * 8]) = v;
            }
        }
        {
            const unsigned short* src = &w2t[(size_t)(cbase + t) * 2048 + hc];
#pragma unroll
            for (int j = 0; j < 8; j++) {
                uint4 v = *reinterpret_cast<const uint4*>(src + j * 8);
                *reinterpret_cast<uint4*>(&w2b[t * 72 + j * 8]) = v;
            }
        }
        __syncthreads();

        v8s a0 = *reinterpret_cast<const v8s*>(&zqb[(16 * w + lo) * 72 +  0 + hi * 8]);
        v8s a1 = *reinterpret_cast<const v8s*>(&zqb[(16 * w + lo) * 72 + 32 + hi * 8]);
#pragma unroll
        for (int ct = 0; ct < 4; ct++) {
            v8s bb0 = *reinterpret_cast<const v8s*>(&w1b[(16 * ct + lo) * 72 +  0 + hi * 8]);
            v8s bb1 = *reinterpret_cast<const v8s*>(&w1b[(16 * ct + lo) * 72 + 32 + hi * 8]);
            v4f acc = (v4f){0.f, 0.f, 0.f, 0.f};
            acc = __builtin_amdgcn_mfma_f32_16x16x32_bf16(a0, bb0, acc, 0, 0, 0);
            acc = __builtin_amdgcn_mfma_f32_16x16x32_bf16(a1, bb1, acc, 0, 0, 0);
            float bias = b1[hc + 16 * ct + lo];
#pragma unroll
            for (int r = 0; r < 4; r++) {
                float hv = fmaxf(acc[r] + bias, 0.f);
                hdb[(16 * w + 4 * hi + r) * 72 + 16 * ct + lo] = f2bf(hv);
            }
        }
        __syncthreads();

#pragma unroll
        for (int kk = 0; kk < 2; kk++) {
            v8s af[4];
#pragma unroll
            for (int rt = 0; rt < 4; rt++)
                af[rt] = *reinterpret_cast<const v8s*>(&hdb[(16 * rt + lo) * 72 + kk * 32 + hi * 8]);
#pragma unroll
            for (int ctl = 0; ctl < 4; ctl++) {
                v8s bf_ = *reinterpret_cast<const v8s*>(&w2b[(64 * w + 16 * ctl + lo) * 72 + kk * 32 + hi * 8]);
#pragma unroll
                for (int rt = 0; rt < 4; rt++)
                    facc[rt][ctl] = __builtin_amdgcn_mfma_f32_16x16x32_bf16(af[rt], bf_, facc[rt][ctl], 0, 0, 0);
            }
        }
    }

#pragma unroll
    for (int ctl = 0; ctl < 4; ctl++) {
        int col = cbase + 64 * w + 16 * ctl + lo;
        float bias = b2[col];
#pragma unroll
        for (int rt = 0; rt < 4; rt++) {
#pragma unroll
            for (int r = 0; r < 4; r++) {
                int row = brow + 16 * rt + 4 * hi + r;
                xr[(size_t)row * NIN + col] = facc[rt][ctl][r] + bias;
            }
        }
    }
}

extern "C" void kernel_launch(void* const* d_in, const int* in_sizes, int n_in,
                              void* d_out, int out_size, void* d_ws, size_t ws_size,
                              hipStream_t stream) {
    (void)in_sizes; (void)n_in; (void)out_size; (void)ws_size;
    const float* x   = (const float*)d_in[0];
    const float* ew1 = (const float*)d_in[1];
    const float* eb1 = (const float*)d_in[2];
    const float* ew2 = (const float*)d_in[3];
    const float* eb2 = (const float*)d_in[4];
    const float* cb  = (const float*)d_in[5];
    const float* dw1 = (const float*)d_in[6];
    const float* db1 = (const float*)d_in[7];
    const float* dw2 = (const float*)d_in[8];
    const float* db2 = (const float*)d_in[9];

    float* out  = (float*)d_out;
    float* part = (float*)d_ws + PART_WS_F;
    float* esq  = (float*)((char*)d_ws + ESQ_WS_B);
    unsigned short* w1t  = (unsigned short*)((char*)d_ws + W1T_WS_B);
    unsigned short* w2t  = (unsigned short*)((char*)d_ws + W2T_WS_B);
    unsigned short* w1hT = (unsigned short*)((char*)d_ws + W1HT_WS_B);
    unsigned short* w1mT = (unsigned short*)((char*)d_ws + W1MT_WS_B);
    unsigned short* w1lT = (unsigned short*)((char*)d_ws + W1LT_WS_B);
    float* flags = (float*)((char*)d_ws + FLAGS_WS_B);

    esq_kernel<<<NEMB / 256, 256, 0, stream>>>(cb, esq);
    prep_w1t<<<512, 256, 0, stream>>>(dw1, w1t);
    prep_w2t<<<8192, 256, 0, stream>>>(dw2, w2t);
    prep_w1split<<<512, 256, 0, stream>>>(ew1, w1hT, w1mT, w1lT);
    encvq_kernel<<<NB / 64, 512, 0, stream>>>(x, w1hT, w1mT, w1lT, eb1, ew2, eb2,
                                              cb, esq, out, part, flags);
    fixup_kernel<<<NB / 16, 256, 0, stream>>>(x, ew1, eb1, ew2, eb2, cb, esq, flags, out);
    loss_kernel<<<1, 64, 0, stream>>>(part, out + LOSS_OFF);
    dec_kernel<<<(NB / 64) * 4, 256, 0, stream>>>(out, w1t, w2t, db1, db2, out + XR_OFF);
}